// Round 9
// baseline (657.326 us; speedup 1.0000x reference)
//
#include <hip/hip_runtime.h>
#include <hip/hip_bf16.h>

#define NN 50000
#define NE 800000

typedef __hip_bfloat16 bf16;
typedef __attribute__((ext_vector_type(8))) short bf16x8s;   // 8 bf16 = 4 VGPRs
typedef __attribute__((ext_vector_type(4))) float f32x4;

// ---- workspace layout (bytes) ----
#define OFF_HP     0L            // hp [NN,128] bf16 : cols 0:64 = h, 64:128 = p
#define OFF_HSUM   12800000L     // hsum [NN,64] f32 (segsum of h over in-edges, by sender)
#define OFF_PSUM   25600000L     // psum [NN,64] f32
#define OFF_ESUM   38400000L     // esum [NN,16] f32 (segsum of raw e_in)
#define OFF_EAGGA  41600000L     // eaggA [NN,64] bf16 (bit-identical to fp32: only consumed via bf16 round)
#define OFF_EAGGB  54400000L     // eaggB [NN,64] bf16
#define OFF_WFMT   67200000L     // formatted weights (516096 B)
#define OFF_ROWPTR 67716096L     // (NN+1) int
#define OFF_COLIDX 67916100L     // NE int (sorted j -> original edge id)
#define OFF_SSEND  71116100L     // NE int (send of sorted edge j)
#define OFF_SEG    74316100L     // NE int (rec of sorted edge j)
#define OFF_CNT    77516100L     // NN int (ends as deg)
#define OFF_BSUM   77716100L     // SCAN_B int block sums

#define SCAN_B 196               // ceil(NN/256)

// ---- formatted-weight element offsets (bf16 elems) ----
#define FW_HE 0
#define FW_EE 8192
#define FW_PE 10240
#define FW_L0 12288
#define LSTR  61440
#define R_HAGG 0        // [hm rows 0:128 ; hm rows 256:320]  K=192  (in: [hsum|psum|eagg])
#define R_HMR  12288    // hm rows 128:256                    K=128  (in: [h|p])
#define R_HU   20480    // hu [128,64]
#define R_EUS  28672    // eu rows 0:64    K=64  (in: hsum_{i+1})
#define R_EUR  32768    // eu rows 64:128  K=64  (in: h_{i+1})
#define R_EUE  36864    // eu rows 128:192 K=64  (in: eagg_i)
#define R_PAGG 40960    // [pm rows 0:64 ; pm rows 128:192]   K=128  (in: [psum|eagg_{i+1}])
#define R_PMR  49152    // pm rows 64:128                     K=64   (in: p)
#define R_PU   53248    // pu [128,64]

#define AGG_STRIDE 72

__device__ __forceinline__ bf16x8s bfrag(const bf16* w, int c, int t, int lane) {
    return *(const bf16x8s*)(w + ((long)(c*4 + t)*64 + lane)*8);
}
__device__ __forceinline__ bf16x8s cvt8(const float* fp) {
    float4 f0 = ((const float4*)fp)[0];
    float4 f1 = ((const float4*)fp)[1];
    bf16 tmp[8];
    tmp[0]=__float2bfloat16(f0.x); tmp[1]=__float2bfloat16(f0.y);
    tmp[2]=__float2bfloat16(f0.z); tmp[3]=__float2bfloat16(f0.w);
    tmp[4]=__float2bfloat16(f1.x); tmp[5]=__float2bfloat16(f1.y);
    tmp[6]=__float2bfloat16(f1.z); tmp[7]=__float2bfloat16(f1.w);
    return *(const bf16x8s*)tmp;
}

// ======================= weight formatting =======================
__global__ __launch_bounds__(256) void wfmt_k(
    const float* __restrict__ he, const float* __restrict__ ee, const float* __restrict__ pe,
    const float* __restrict__ hm, const float* __restrict__ hu, const float* __restrict__ eu,
    const float* __restrict__ pm, const float* __restrict__ pu, bf16* __restrict__ wf)
{
    int s = blockIdx.x;
    const float* src = nullptr; int rowoff = 0, Ksrc = 0, Kpad = 0, mode = 0, split = 0, gap = 0; long doff = 0;
    if      (s == 0) { src = he; Ksrc = 128; Kpad = 128; doff = FW_HE; }
    else if (s == 1) { src = ee; Ksrc = 16;  Kpad = 32;  doff = FW_EE; }
    else if (s == 2) { src = pe; Ksrc = 16;  Kpad = 32;  doff = FW_PE; }
    else {
        int i = (s - 3) / 9, g = (s - 3) % 9;
        long base = FW_L0 + (long)i*LSTR;
        const float* HM = hm + (long)i*320*64;
        const float* HU = hu + (long)i*128*64;
        const float* EU = eu + (long)i*192*64;
        const float* PM = pm + (long)i*192*64;
        const float* PU = pu + (long)i*128*64;
        switch (g) {
          case 0:  src=HM; mode=4; split=128; gap=128; Kpad=192; doff=base+R_HAGG; break;
          case 1:  src=HM; rowoff=128; Ksrc=128; Kpad=128; doff=base+R_HMR;  break;
          case 2:  src=HU; rowoff=0;   Ksrc=128; Kpad=128; doff=base+R_HU;   break;
          case 3:  src=EU; rowoff=0;   Ksrc=64;  Kpad=64;  doff=base+R_EUS;  break;
          case 4:  src=EU; rowoff=64;  Ksrc=64;  Kpad=64;  doff=base+R_EUR;  break;
          case 5:  src=EU; rowoff=128; Ksrc=64;  Kpad=64;  doff=base+R_EUE;  break;
          case 6:  src=PM; mode=4; split=64; gap=64; Kpad=128; doff=base+R_PAGG; break;
          case 7:  src=PM; rowoff=64;  Ksrc=64;  Kpad=64;  doff=base+R_PMR;  break;
          default: src=PU; rowoff=0;   Ksrc=128; Kpad=128; doff=base+R_PU;   break;
        }
    }
    int total = Kpad * 64;
    for (int idx = threadIdx.x; idx < total; idx += 256) {
        int j = idx & 7, l = (idx >> 3) & 63, ct = idx >> 9;
        int c = ct >> 2, t = ct & 3;
        int k = c*32 + (l >> 4)*8 + j;
        int n = t*16 + (l & 15);
        float v;
        if (mode == 4) v = src[(long)(k + (k >= split ? gap : 0))*64 + n];
        else           v = (k < Ksrc) ? src[(long)(rowoff + k)*64 + n] : 0.f;
        wf[doff + idx] = __float2bfloat16(v);
    }
}

// ======================= CSR build =======================
__global__ __launch_bounds__(256) void hist_k(const int* __restrict__ rec, int* __restrict__ cnt)
{
    int e = blockIdx.x*256 + threadIdx.x;
    if (e < NE) atomicAdd(&cnt[rec[e]], 1);
}

__global__ __launch_bounds__(256) void scan1_k(const int* __restrict__ cnt, int* __restrict__ bsum)
{
    __shared__ int sdata[256];
    int tid = threadIdx.x;
    int i = blockIdx.x*256 + tid;
    sdata[tid] = (i < NN) ? cnt[i] : 0;
    __syncthreads();
    #pragma unroll
    for (int off = 128; off > 0; off >>= 1) {
        if (tid < off) sdata[tid] += sdata[tid + off];
        __syncthreads();
    }
    if (tid == 0) bsum[blockIdx.x] = sdata[0];
}

__global__ __launch_bounds__(256) void scan2_k(int* __restrict__ bsum)
{
    __shared__ int sdata[256];
    int tid = threadIdx.x;
    int v = (tid < SCAN_B) ? bsum[tid] : 0;
    sdata[tid] = v;
    __syncthreads();
    #pragma unroll
    for (int off = 1; off < 256; off <<= 1) {
        int t = (tid >= off) ? sdata[tid - off] : 0;
        __syncthreads();
        sdata[tid] += t;
        __syncthreads();
    }
    if (tid < SCAN_B) bsum[tid] = sdata[tid] - v;   // exclusive
}

__global__ __launch_bounds__(256) void scan3_k(const int* __restrict__ cnt,
    const int* __restrict__ bsum, int* __restrict__ rowptr)
{
    __shared__ int sdata[256];
    int tid = threadIdx.x;
    int i = blockIdx.x*256 + tid;
    sdata[tid] = (i < NN) ? cnt[i] : 0;
    __syncthreads();
    #pragma unroll
    for (int off = 1; off < 256; off <<= 1) {
        int t = (tid >= off) ? sdata[tid - off] : 0;
        __syncthreads();
        sdata[tid] += t;
        __syncthreads();
    }
    if (i < NN) rowptr[i + 1] = sdata[tid] + bsum[blockIdx.x];
    if (i == 0) rowptr[0] = 0;
}

// scatter colidx (plain store — NT store measured WORSE: 53->60us, round-7 post-mortem)
__global__ __launch_bounds__(256) void scatter_k(const int* __restrict__ rec,
    const int* __restrict__ rowptr, int* __restrict__ cursor, int* __restrict__ colidx)
{
    int e = blockIdx.x*256 + threadIdx.x;
    if (e < NE) {
        int r = rec[e];
        int pos = atomicAdd(&cursor[r], 1);
        colidx[rowptr[r] + pos] = e;
    }
}

// segfill: per-node run expansion (coalescing-friendly sequential writes)
__global__ __launch_bounds__(256) void segfill_k(const int* __restrict__ rowptr, int* __restrict__ seg)
{
    int n = blockIdx.x*256 + threadIdx.x;
    if (n < NN) {
        int b = rowptr[n], e = rowptr[n + 1];
        for (int j = b; j < e; ++j) seg[j] = n;
    }
}

// ======================= gsum64: segsum of hp[ssend, coff:coff+64] (+BOTH: +64 half)
// lane = column (atomic flushes are one CONTIGUOUS 256B instruction — critical:
// strided flushes cost 6x HBM write amplification, round-5 post-mortem).
// Edge-partitioned (64 edges/wave, 12500 waves — MLP; node-partition at 1/4 the
// waves was 3-5x slower, round-7 post-mortem). ids LDS-staged. DEPTH-deep
// double-buffered register prefetch (latency-bound gather: deeper = more MLP).
template <int DEPTH, bool BOTH>
__global__ __launch_bounds__(256) void gsum64_k(const bf16* __restrict__ hp, int coff,
    const int* __restrict__ ssend, const int* __restrict__ seg,
    float* __restrict__ out1, float* __restrict__ out2)
{
    __shared__ int s_ids[256];
    __shared__ int s_seg[256];
    int tid = threadIdx.x, lane = tid & 63, wv = tid >> 6;
    int gbase = blockIdx.x*256;
    s_ids[tid] = ssend[gbase + tid];
    s_seg[tid] = seg[gbase + tid];
    __syncthreads();
    int j0 = wv*64;
    const bf16* base = hp + coff + lane;
    constexpr int NB = 64 / DEPTH;

    unsigned short va[DEPTH], vb[DEPTH];
    unsigned short wa[BOTH ? DEPTH : 1], wb[BOTH ? DEPTH : 1];
    #pragma unroll
    for (int k = 0; k < DEPTH; ++k) {
        long o = (long)s_ids[j0 + k]*128;
        va[k] = *(const unsigned short*)(base + o);
        if (BOTH) wa[k] = *(const unsigned short*)(base + o + 64);
    }

    float a = 0.f, b2 = 0.f;
    int cur = s_seg[j0];
    #pragma unroll
    for (int b = 0; b < NB; ++b) {
        if (b < NB - 1) {
            #pragma unroll
            for (int k = 0; k < DEPTH; ++k) {
                long o = (long)s_ids[j0 + (b+1)*DEPTH + k]*128;
                vb[k] = *(const unsigned short*)(base + o);
                if (BOTH) wb[k] = *(const unsigned short*)(base + o + 64);
            }
        }
        #pragma unroll
        for (int k = 0; k < DEPTH; ++k) {
            int n = s_seg[j0 + b*DEPTH + k];
            if (n != cur) {
                atomicAdd(&out1[(long)cur*64 + lane], a);
                if (BOTH) atomicAdd(&out2[(long)cur*64 + lane], b2);
                a = 0.f; b2 = 0.f; cur = n;
            }
            a += __uint_as_float(((unsigned)va[k]) << 16);
            if (BOTH) b2 += __uint_as_float(((unsigned)wa[k]) << 16);
        }
        if (b < NB - 1) {
            #pragma unroll
            for (int k = 0; k < DEPTH; ++k) { va[k] = vb[k]; if (BOTH) wa[k] = wb[k]; }
        }
    }
    atomicAdd(&out1[(long)cur*64 + lane], a);
    if (BOTH) atomicAdd(&out2[(long)cur*64 + lane], b2);
}

// ======================= esum: segsum of raw e_in (16-wide) + fused ssend fill
__global__ __launch_bounds__(256) void esum_k(const float* __restrict__ e_in,
    const int* __restrict__ colidx, const int* __restrict__ seg, const int* __restrict__ send,
    int* __restrict__ ssend, float* __restrict__ esum)
{
    __shared__ int s_ids[256];
    __shared__ int s_seg[256];
    int tid = threadIdx.x;
    int gbase = blockIdx.x*256;
    int id = colidx[gbase + tid];
    s_ids[tid] = id;
    s_seg[tid] = seg[gbase + tid];
    ssend[gbase + tid] = send[id];
    __syncthreads();
    int grp = tid >> 4, c = tid & 15;
    int j0 = grp*16;
    float vv[16];
    #pragma unroll
    for (int jj = 0; jj < 16; ++jj) vv[jj] = e_in[(long)s_ids[j0 + jj]*16 + c];
    float a = 0.f;
    int cur = s_seg[j0];
    #pragma unroll
    for (int jj = 0; jj < 16; ++jj) {
        int n = s_seg[j0 + jj];
        if (n != cur) { atomicAdd(&esum[(long)cur*16 + c], a); a = 0.f; cur = n; }
        a += vv[jj];
    }
    atomicAdd(&esum[(long)cur*16 + c], a);
}

// ======================= eembn: eagg0 = esum@EE + deg*ee_b (node-level, bf16 out) ==========
__global__ __launch_bounds__(256) void eembn_k(const float* __restrict__ esum,
    const int* __restrict__ deg, const bf16* __restrict__ wEE, const float* __restrict__ ee_b,
    bf16* __restrict__ eagg)
{
    int tid = threadIdx.x, lane = tid & 63, wv = tid >> 6;
    int l15 = lane & 15, q = lane >> 4;
    int row = blockIdx.x*64 + wv*16 + l15;
    int rc = (row < NN) ? row : NN - 1;
    f32x4 acc[4];
    #pragma unroll
    for (int t = 0; t < 4; ++t) { acc[t][0]=0; acc[t][1]=0; acc[t][2]=0; acc[t][3]=0; }
    {
        bf16x8s af = {0,0,0,0,0,0,0,0};
        if (q < 2) af = cvt8(esum + (long)rc*16 + q*8);
        #pragma unroll
        for (int t = 0; t < 4; ++t)
            acc[t] = __builtin_amdgcn_mfma_f32_16x16x32_bf16(af, bfrag(wEE, 0, t, lane), acc[t], 0, 0, 0);
    }
    float bv[4];
    #pragma unroll
    for (int t = 0; t < 4; ++t) bv[t] = ee_b[t*16 + l15];
    #pragma unroll
    for (int r = 0; r < 4; ++r) {
        int ro = blockIdx.x*64 + wv*16 + q*4 + r;
        if (ro < NN) {
            float dg = (float)deg[ro];
            #pragma unroll
            for (int t = 0; t < 4; ++t)
                eagg[(long)ro*64 + t*16 + l15] = __float2bfloat16(acc[t][r] + dg*bv[t]);
        }
    }
}

// ======================= hpemb: h & p embeddings in one pass =======================
__global__ __launch_bounds__(256) void hpemb_k(const float* __restrict__ h_in,
    const float* __restrict__ p_in,
    const bf16* __restrict__ wHE, const bf16* __restrict__ wPE,
    const float* __restrict__ he_b, const float* __restrict__ pe_b, bf16* __restrict__ hp)
{
    int tid = threadIdx.x, lane = tid & 63, wv = tid >> 6;
    int l15 = lane & 15, q = lane >> 4;
    int row = blockIdx.x*64 + wv*16 + l15;
    int rc = (row < NN) ? row : NN - 1;
    f32x4 aH[4], aP[4];
    #pragma unroll
    for (int t = 0; t < 4; ++t) {
        float bh = he_b[t*16 + l15], bp = pe_b[t*16 + l15];
        aH[t][0]=bh; aH[t][1]=bh; aH[t][2]=bh; aH[t][3]=bh;
        aP[t][0]=bp; aP[t][1]=bp; aP[t][2]=bp; aP[t][3]=bp;
    }
    #pragma unroll
    for (int c = 0; c < 4; ++c) {
        bf16x8s af = cvt8(h_in + (long)rc*128 + c*32 + q*8);
        #pragma unroll
        for (int t = 0; t < 4; ++t)
            aH[t] = __builtin_amdgcn_mfma_f32_16x16x32_bf16(af, bfrag(wHE, c, t, lane), aH[t], 0, 0, 0);
    }
    {
        bf16x8s af = {0,0,0,0,0,0,0,0};
        if (q < 2) af = cvt8(p_in + (long)rc*16 + q*8);
        #pragma unroll
        for (int t = 0; t < 4; ++t)
            aP[t] = __builtin_amdgcn_mfma_f32_16x16x32_bf16(af, bfrag(wPE, 0, t, lane), aP[t], 0, 0, 0);
    }
    #pragma unroll
    for (int r = 0; r < 4; ++r) {
        int ro = blockIdx.x*64 + wv*16 + q*4 + r;
        if (ro < NN)
            #pragma unroll
            for (int t = 0; t < 4; ++t) {
                hp[(long)ro*128 + t*16 + l15]      = __float2bfloat16(aH[t][r]);
                hp[(long)ro*128 + 64 + t*16 + l15] = __float2bfloat16(aP[t][r]);
            }
    }
}

// hfuse: agg = [hsum|psum|eagg]@HAGG + deg*([h|p]@HMR + hm_b);  h_new = [h|agg]@HU + hu_b
//        zero-fuse: clears hsum (last reader) for the next gsum
__global__ __launch_bounds__(256) void hfuse_k(
    bf16* __restrict__ hp, float* __restrict__ hsum, const float* __restrict__ psum,
    const bf16* __restrict__ eagg, const int* __restrict__ deg,
    const bf16* __restrict__ wAGG, const bf16* __restrict__ wR, const float* __restrict__ mb,
    const bf16* __restrict__ wU, const float* __restrict__ ub, float* __restrict__ out2)
{
    __shared__ __align__(16) bf16 sAgg[64 * AGG_STRIDE];
    int tid = threadIdx.x, lane = tid & 63, wv = tid >> 6;
    int l15 = lane & 15, q = lane >> 4;
    int row = blockIdx.x*64 + wv*16 + l15;
    int rc = (row < NN) ? row : NN - 1;

    f32x4 aA[4], aR[4];
    #pragma unroll
    for (int t = 0; t < 4; ++t) {
        aA[t][0]=0;aA[t][1]=0;aA[t][2]=0;aA[t][3]=0;
        aR[t][0]=0;aR[t][1]=0;aR[t][2]=0;aR[t][3]=0;
    }
    #pragma unroll
    for (int c = 0; c < 6; ++c) {
        bf16x8s af = (c < 2) ? cvt8(hsum + (long)rc*64 + c*32 + q*8)
                   : (c < 4) ? cvt8(psum + (long)rc*64 + (c-2)*32 + q*8)
                             : *(const bf16x8s*)(eagg + (long)rc*64 + (c-4)*32 + q*8);
        #pragma unroll
        for (int t = 0; t < 4; ++t)
            aA[t] = __builtin_amdgcn_mfma_f32_16x16x32_bf16(af, bfrag(wAGG, c, t, lane), aA[t], 0, 0, 0);
    }
    // zero-fuse hsum (owner rows only)
    if (row < NN) {
        float4 z4 = make_float4(0.f, 0.f, 0.f, 0.f);
        #pragma unroll
        for (int c = 0; c < 2; ++c) {
            *(float4*)(hsum + (long)rc*64 + c*32 + q*8)     = z4;
            *(float4*)(hsum + (long)rc*64 + c*32 + q*8 + 4) = z4;
        }
    }
    #pragma unroll
    for (int c = 0; c < 4; ++c) {
        bf16x8s af = *(const bf16x8s*)(hp + (long)rc*128 + c*32 + q*8);
        #pragma unroll
        for (int t = 0; t < 4; ++t)
            aR[t] = __builtin_amdgcn_mfma_f32_16x16x32_bf16(af, bfrag(wR, c, t, lane), aR[t], 0, 0, 0);
    }
    float mbv[4];
    #pragma unroll
    for (int t = 0; t < 4; ++t) mbv[t] = mb[t*16 + l15];
    #pragma unroll
    for (int r = 0; r < 4; ++r) {
        int ro = blockIdx.x*64 + wv*16 + q*4 + r;
        float dg = (float)deg[(ro < NN) ? ro : NN - 1];
        #pragma unroll
        for (int t = 0; t < 4; ++t)
            sAgg[(wv*16 + q*4 + r)*AGG_STRIDE + t*16 + l15] =
                __float2bfloat16(aA[t][r] + dg*(aR[t][r] + mbv[t]));
    }
    __syncthreads();
    f32x4 acc[4];
    #pragma unroll
    for (int t = 0; t < 4; ++t) { float b = ub[t*16 + l15]; acc[t][0]=b; acc[t][1]=b; acc[t][2]=b; acc[t][3]=b; }
    #pragma unroll
    for (int c = 0; c < 4; ++c) {
        bf16x8s af = (c < 2) ? *(const bf16x8s*)(hp + (long)rc*128 + c*32 + q*8)
                             : *(const bf16x8s*)(sAgg + (wv*16 + l15)*AGG_STRIDE + (c-2)*32 + q*8);
        #pragma unroll
        for (int t = 0; t < 4; ++t)
            acc[t] = __builtin_amdgcn_mfma_f32_16x16x32_bf16(af, bfrag(wU, c, t, lane), acc[t], 0, 0, 0);
    }
    #pragma unroll
    for (int r = 0; r < 4; ++r) {
        int ro = blockIdx.x*64 + wv*16 + q*4 + r;
        if (ro < NN) {
            #pragma unroll
            for (int t = 0; t < 4; ++t) {
                float fv = acc[t][r];
                hp[(long)ro*128 + t*16 + l15] = __float2bfloat16(fv);
                if (out2) out2[(long)ro*64 + t*16 + l15] = fv;
            }
        }
    }
}

// pfuse: eaggNew = hsumN@EUS + deg*(h_new@EUR + eu_b) + eaggIn@EUE   (stored bf16)
//        agg = [psum|eaggNew]@PAGG + deg*(p@PMR + pm_b);  p_new = [p|agg]@PU + pu_b
//        zero-fuse: clears psum (last reader)
__global__ __launch_bounds__(256) void pfuse_k(
    bf16* __restrict__ hp, const float* __restrict__ hsumN, float* __restrict__ psum,
    const bf16* __restrict__ eaggIn, bf16* __restrict__ eaggOut, const int* __restrict__ deg,
    const bf16* __restrict__ wEUS, const bf16* __restrict__ wEUR, const bf16* __restrict__ wEUE,
    const float* __restrict__ eub,
    const bf16* __restrict__ wAGG, const bf16* __restrict__ wR, const float* __restrict__ mb,
    const bf16* __restrict__ wU, const float* __restrict__ ub, float* __restrict__ out2)
{
    __shared__ __align__(16) bf16 sE[64 * AGG_STRIDE];
    __shared__ __align__(16) bf16 sAgg[64 * AGG_STRIDE];
    int tid = threadIdx.x, lane = tid & 63, wv = tid >> 6;
    int l15 = lane & 15, q = lane >> 4;
    int row = blockIdx.x*64 + wv*16 + l15;
    int rc = (row < NN) ? row : NN - 1;

    // ---- eagg recurrence ----
    f32x4 aE[4], aH[4];
    #pragma unroll
    for (int t = 0; t < 4; ++t) {
        aE[t][0]=0;aE[t][1]=0;aE[t][2]=0;aE[t][3]=0;
        aH[t][0]=0;aH[t][1]=0;aH[t][2]=0;aH[t][3]=0;
    }
    #pragma unroll
    for (int c = 0; c < 4; ++c) {
        bf16x8s af = (c < 2) ? cvt8(hsumN + (long)rc*64 + c*32 + q*8)
                             : *(const bf16x8s*)(eaggIn + (long)rc*64 + (c-2)*32 + q*8);
        #pragma unroll
        for (int t = 0; t < 4; ++t) {
            bf16x8s w = (c < 2) ? bfrag(wEUS, c, t, lane) : bfrag(wEUE, c-2, t, lane);
            aE[t] = __builtin_amdgcn_mfma_f32_16x16x32_bf16(af, w, aE[t], 0, 0, 0);
        }
    }
    #pragma unroll
    for (int c = 0; c < 2; ++c) {
        bf16x8s af = *(const bf16x8s*)(hp + (long)rc*128 + c*32 + q*8);   // h_new
        #pragma unroll
        for (int t = 0; t < 4; ++t)
            aH[t] = __builtin_amdgcn_mfma_f32_16x16x32_bf16(af, bfrag(wEUR, c, t, lane), aH[t], 0, 0, 0);
    }
    float ebv[4];
    #pragma unroll
    for (int t = 0; t < 4; ++t) ebv[t] = eub[t*16 + l15];
    #pragma unroll
    for (int r = 0; r < 4; ++r) {
        int ro = blockIdx.x*64 + wv*16 + q*4 + r;
        float dg = (float)deg[(ro < NN) ? ro : NN - 1];
        #pragma unroll
        for (int t = 0; t < 4; ++t) {
            bf16 ev = __float2bfloat16(aE[t][r] + dg*(aH[t][r] + ebv[t]));
            sE[(wv*16 + q*4 + r)*AGG_STRIDE + t*16 + l15] = ev;
            if (eaggOut && ro < NN) eaggOut[(long)ro*64 + t*16 + l15] = ev;
        }
    }
    __syncthreads();

    // ---- p aggregate compose ----
    f32x4 aA[4], aR[4];
    #pragma unroll
    for (int t = 0; t < 4; ++t) {
        aA[t][0]=0;aA[t][1]=0;aA[t][2]=0;aA[t][3]=0;
        aR[t][0]=0;aR[t][1]=0;aR[t][2]=0;aR[t][3]=0;
    }
    #pragma unroll
    for (int c = 0; c < 4; ++c) {
        bf16x8s af = (c < 2) ? cvt8(psum + (long)rc*64 + c*32 + q*8)
                             : *(const bf16x8s*)(sE + (wv*16 + l15)*AGG_STRIDE + (c-2)*32 + q*8);
        #pragma unroll
        for (int t = 0; t < 4; ++t)
            aA[t] = __builtin_amdgcn_mfma_f32_16x16x32_bf16(af, bfrag(wAGG, c, t, lane), aA[t], 0, 0, 0);
    }
    // zero-fuse psum (owner rows only)
    if (row < NN) {
        float4 z4 = make_float4(0.f, 0.f, 0.f, 0.f);
        #pragma unroll
        for (int c = 0; c < 2; ++c) {
            *(float4*)(psum + (long)rc*64 + c*32 + q*8)     = z4;
            *(float4*)(psum + (long)rc*64 + c*32 + q*8 + 4) = z4;
        }
    }
    #pragma unroll
    for (int c = 0; c < 2; ++c) {
        bf16x8s af = *(const bf16x8s*)(hp + (long)rc*128 + 64 + c*32 + q*8);
        #pragma unroll
        for (int t = 0; t < 4; ++t)
            aR[t] = __builtin_amdgcn_mfma_f32_16x16x32_bf16(af, bfrag(wR, c, t, lane), aR[t], 0, 0, 0);
    }
    float mbv[4];
    #pragma unroll
    for (int t = 0; t < 4; ++t) mbv[t] = mb[t*16 + l15];
    #pragma unroll
    for (int r = 0; r < 4; ++r) {
        int ro = blockIdx.x*64 + wv*16 + q*4 + r;
        float dg = (float)deg[(ro < NN) ? ro : NN - 1];
        #pragma unroll
        for (int t = 0; t < 4; ++t)
            sAgg[(wv*16 + q*4 + r)*AGG_STRIDE + t*16 + l15] =
                __float2bfloat16(aA[t][r] + dg*(aR[t][r] + mbv[t]));
    }
    __syncthreads();
    f32x4 acc[4];
    #pragma unroll
    for (int t = 0; t < 4; ++t) { float b = ub[t*16 + l15]; acc[t][0]=b; acc[t][1]=b; acc[t][2]=b; acc[t][3]=b; }
    #pragma unroll
    for (int c = 0; c < 4; ++c) {
        bf16x8s af = (c < 2) ? *(const bf16x8s*)(hp + (long)rc*128 + 64 + c*32 + q*8)
                             : *(const bf16x8s*)(sAgg + (wv*16 + l15)*AGG_STRIDE + (c-2)*32 + q*8);
        #pragma unroll
        for (int t = 0; t < 4; ++t)
            acc[t] = __builtin_amdgcn_mfma_f32_16x16x32_bf16(af, bfrag(wU, c, t, lane), acc[t], 0, 0, 0);
    }
    #pragma unroll
    for (int r = 0; r < 4; ++r) {
        int ro = blockIdx.x*64 + wv*16 + q*4 + r;
        if (ro < NN) {
            #pragma unroll
            for (int t = 0; t < 4; ++t) {
                float fv = acc[t][r];
                hp[(long)ro*128 + 64 + t*16 + l15] = __float2bfloat16(fv);
                if (out2) out2[(long)ro*64 + t*16 + l15] = fv;
            }
        }
    }
}

// ======================= launch =======================
extern "C" void kernel_launch(void* const* d_in, const int* in_sizes, int n_in,
                              void* d_out, int out_size, void* d_ws, size_t ws_size,
                              hipStream_t stream)
{
    (void)in_sizes; (void)n_in; (void)out_size; (void)ws_size;
    const float* h_in = (const float*)d_in[0];
    const float* e_in = (const float*)d_in[1];
    const float* p_in = (const float*)d_in[2];
    const int*  ei   = (const int*)d_in[3];
    const int* send = ei;
    const int* rec  = ei + NE;
    const float* he_W = (const float*)d_in[4];  const float* he_b = (const float*)d_in[5];
    const float* ee_W = (const float*)d_in[6];  const float* ee_b = (const float*)d_in[7];
    const float* pe_W = (const float*)d_in[8];  const float* pe_b = (const float*)d_in[9];
    const float* hm_W = (const float*)d_in[10]; const float* hm_b = (const float*)d_in[11];
    const float* hu_W = (const float*)d_in[12]; const float* hu_b = (const float*)d_in[13];
    const float* eu_W = (const float*)d_in[14]; const float* eu_b = (const float*)d_in[15];
    const float* pm_W = (const float*)d_in[16]; const float* pm_b = (const float*)d_in[17];
    const float* pu_W = (const float*)d_in[18]; const float* pu_b = (const float*)d_in[19];

    char* ws = (char*)d_ws;
    bf16* hp     = (bf16*)(ws + OFF_HP);
    float* hsum  = (float*)(ws + OFF_HSUM);
    float* psum  = (float*)(ws + OFF_PSUM);
    float* esum  = (float*)(ws + OFF_ESUM);
    bf16* eaggA  = (bf16*)(ws + OFF_EAGGA);
    bf16* eaggB  = (bf16*)(ws + OFF_EAGGB);
    bf16* wf     = (bf16*)(ws + OFF_WFMT);
    int* rowptr  = (int*)(ws + OFF_ROWPTR);
    int* colidx  = (int*)(ws + OFF_COLIDX);
    int* ssend   = (int*)(ws + OFF_SSEND);
    int* segarr  = (int*)(ws + OFF_SEG);
    int* cnt     = (int*)(ws + OFF_CNT);
    int* bsum    = (int*)(ws + OFF_BSUM);
    float* dout  = (float*)d_out;

    const int EB   = NE / 256;          // 3125
    const int NB64 = (NN + 63) / 64;    // 782

    // CSR build; cnt ends as deg
    (void)hipMemsetAsync(cnt, 0, NN * sizeof(int), stream);
    hist_k<<<EB, 256, 0, stream>>>(rec, cnt);
    scan1_k<<<SCAN_B, 256, 0, stream>>>(cnt, bsum);
    scan2_k<<<1, 256, 0, stream>>>(bsum);
    scan3_k<<<SCAN_B, 256, 0, stream>>>(cnt, bsum, rowptr);
    (void)hipMemsetAsync(cnt, 0, NN * sizeof(int), stream);
    scatter_k<<<EB, 256, 0, stream>>>(rec, rowptr, cnt, colidx);
    segfill_k<<<SCAN_B, 256, 0, stream>>>(rowptr, segarr);

    // zero hsum + psum + esum (contiguous; zero-fuse maintains hsum/psum per layer)
    (void)hipMemsetAsync(hsum, 0, (long)NN*(64 + 64 + 16)*sizeof(float), stream);

    // esum + ssend fill (one pass over colidx)
    esum_k<<<EB, 256, 0, stream>>>(e_in, colidx, segarr, send, ssend, esum);

    wfmt_k<<<39, 256, 0, stream>>>(he_W, ee_W, pe_W, hm_W, hu_W, eu_W, pm_W, pu_W, wf);

    // embeddings + bootstrap aggregates (hsum & psum in ONE pass)
    hpemb_k<<<NB64, 256, 0, stream>>>(h_in, p_in, wf + FW_HE, wf + FW_PE, he_b, pe_b, hp);
    eembn_k<<<NB64, 256, 0, stream>>>(esum, cnt, wf + FW_EE, ee_b, eaggA);
    gsum64_k<16, true><<<EB, 256, 0, stream>>>(hp, 0, ssend, segarr, hsum, psum);

    bf16* eA = eaggA;
    bf16* eB = eaggB;
    for (int i = 0; i < 4; ++i) {
        long base = FW_L0 + (long)i*LSTR;
        // h update (consumes hsum_i, psum_i, eagg_i; zeroes hsum)
        hfuse_k<<<NB64, 256, 0, stream>>>(hp, hsum, psum, eA, cnt,
            wf + base + R_HAGG, wf + base + R_HMR, hm_b + i*64,
            wf + base + R_HU, hu_b + i*64,
            (i == 3) ? dout : nullptr);
        // hsum_{i+1} = segsum(h_new[send])
        gsum64_k<32, false><<<EB, 256, 0, stream>>>(hp, 0, ssend, segarr, hsum, nullptr);
        // p update (computes eagg_{i+1} -> eB; consumes psum_i; zeroes psum)
        pfuse_k<<<NB64, 256, 0, stream>>>(hp, hsum, psum, eA, (i < 3) ? eB : nullptr, cnt,
            wf + base + R_EUS, wf + base + R_EUR, wf + base + R_EUE, eu_b + i*64,
            wf + base + R_PAGG, wf + base + R_PMR, pm_b + i*64,
            wf + base + R_PU, pu_b + i*64,
            (i == 3) ? dout + (long)NN*64 : nullptr);
        // psum_{i+1} = segsum(p_new[send])
        if (i < 3)
            gsum64_k<32, false><<<EB, 256, 0, stream>>>(hp, 64, ssend, segarr, psum, nullptr);
        bf16* tmp = eA; eA = eB; eB = tmp;
    }
}

// Round 10
// 622.339 us; speedup vs baseline: 1.0562x; 1.0562x over previous
//
#include <hip/hip_runtime.h>
#include <hip/hip_bf16.h>
#include <hip/hip_cooperative_groups.h>
namespace cg = cooperative_groups;

#define NN 50000
#define NE 800000
#define NB64 782                 // ceil(NN/64)
#define EB   3125                // NE/256

typedef __hip_bfloat16 bf16;
typedef __attribute__((ext_vector_type(8))) short bf16x8s;   // 8 bf16 = 4 VGPRs
typedef __attribute__((ext_vector_type(4))) float f32x4;

// ---- workspace layout (bytes) ----
#define OFF_HP     0L            // hp [NN,128] bf16 : cols 0:64 = h, 64:128 = p
#define OFF_HSUM   12800000L     // hsum [NN,64] f32
#define OFF_PSUM   25600000L     // psum [NN,64] f32
#define OFF_ESUM   38400000L     // esum [NN,16] f32
#define OFF_EAGGA  41600000L     // eaggA [NN,64] bf16
#define OFF_EAGGB  54400000L     // eaggB [NN,64] bf16
#define OFF_WFMT   67200000L     // formatted weights
#define OFF_ROWPTR 67716096L     // (NN+1) int
#define OFF_COLIDX 67916100L     // NE int
#define OFF_SSEND  71116100L     // NE int
#define OFF_SEG    74316100L     // NE int
#define OFF_CNT    77516100L     // NN int (ends as deg)
#define OFF_BSUM   77716100L     // SCAN_B int

#define SCAN_B 196               // ceil(NN/256)

// ---- formatted-weight element offsets (bf16 elems) ----
#define FW_HE 0
#define FW_EE 8192
#define FW_PE 10240
#define FW_L0 12288
#define LSTR  61440
#define R_HAGG 0
#define R_HMR  12288
#define R_HU   20480
#define R_EUS  28672
#define R_EUR  32768
#define R_EUE  36864
#define R_PAGG 40960
#define R_PMR  49152
#define R_PU   53248

#define AGG_STRIDE 72

__device__ __forceinline__ bf16x8s bfrag(const bf16* w, int c, int t, int lane) {
    return *(const bf16x8s*)(w + ((long)(c*4 + t)*64 + lane)*8);
}
__device__ __forceinline__ bf16x8s cvt8(const float* fp) {
    float4 f0 = ((const float4*)fp)[0];
    float4 f1 = ((const float4*)fp)[1];
    bf16 tmp[8];
    tmp[0]=__float2bfloat16(f0.x); tmp[1]=__float2bfloat16(f0.y);
    tmp[2]=__float2bfloat16(f0.z); tmp[3]=__float2bfloat16(f0.w);
    tmp[4]=__float2bfloat16(f1.x); tmp[5]=__float2bfloat16(f1.y);
    tmp[6]=__float2bfloat16(f1.z); tmp[7]=__float2bfloat16(f1.w);
    return *(const bf16x8s*)tmp;
}

// ======================= weight formatting =======================
__global__ __launch_bounds__(256) void wfmt_k(
    const float* __restrict__ he, const float* __restrict__ ee, const float* __restrict__ pe,
    const float* __restrict__ hm, const float* __restrict__ hu, const float* __restrict__ eu,
    const float* __restrict__ pm, const float* __restrict__ pu, bf16* __restrict__ wf)
{
    int s = blockIdx.x;
    const float* src = nullptr; int rowoff = 0, Ksrc = 0, Kpad = 0, mode = 0, split = 0, gap = 0; long doff = 0;
    if      (s == 0) { src = he; Ksrc = 128; Kpad = 128; doff = FW_HE; }
    else if (s == 1) { src = ee; Ksrc = 16;  Kpad = 32;  doff = FW_EE; }
    else if (s == 2) { src = pe; Ksrc = 16;  Kpad = 32;  doff = FW_PE; }
    else {
        int i = (s - 3) / 9, g = (s - 3) % 9;
        long base = FW_L0 + (long)i*LSTR;
        const float* HM = hm + (long)i*320*64;
        const float* HU = hu + (long)i*128*64;
        const float* EU = eu + (long)i*192*64;
        const float* PM = pm + (long)i*192*64;
        const float* PU = pu + (long)i*128*64;
        switch (g) {
          case 0:  src=HM; mode=4; split=128; gap=128; Kpad=192; doff=base+R_HAGG; break;
          case 1:  src=HM; rowoff=128; Ksrc=128; Kpad=128; doff=base+R_HMR;  break;
          case 2:  src=HU; rowoff=0;   Ksrc=128; Kpad=128; doff=base+R_HU;   break;
          case 3:  src=EU; rowoff=0;   Ksrc=64;  Kpad=64;  doff=base+R_EUS;  break;
          case 4:  src=EU; rowoff=64;  Ksrc=64;  Kpad=64;  doff=base+R_EUR;  break;
          case 5:  src=EU; rowoff=128; Ksrc=64;  Kpad=64;  doff=base+R_EUE;  break;
          case 6:  src=PM; mode=4; split=64; gap=64; Kpad=128; doff=base+R_PAGG; break;
          case 7:  src=PM; rowoff=64;  Ksrc=64;  Kpad=64;  doff=base+R_PMR;  break;
          default: src=PU; rowoff=0;   Ksrc=128; Kpad=128; doff=base+R_PU;   break;
        }
    }
    int total = Kpad * 64;
    for (int idx = threadIdx.x; idx < total; idx += 256) {
        int j = idx & 7, l = (idx >> 3) & 63, ct = idx >> 9;
        int c = ct >> 2, t = ct & 3;
        int k = c*32 + (l >> 4)*8 + j;
        int n = t*16 + (l & 15);
        float v;
        if (mode == 4) v = src[(long)(k + (k >= split ? gap : 0))*64 + n];
        else           v = (k < Ksrc) ? src[(long)(rowoff + k)*64 + n] : 0.f;
        wf[doff + idx] = __float2bfloat16(v);
    }
}

// ======================= CSR build =======================
__global__ __launch_bounds__(256) void hist_k(const int* __restrict__ rec, int* __restrict__ cnt)
{
    int e = blockIdx.x*256 + threadIdx.x;
    if (e < NE) atomicAdd(&cnt[rec[e]], 1);
}

__global__ __launch_bounds__(256) void scan1_k(const int* __restrict__ cnt, int* __restrict__ bsum)
{
    __shared__ int sdata[256];
    int tid = threadIdx.x;
    int i = blockIdx.x*256 + tid;
    sdata[tid] = (i < NN) ? cnt[i] : 0;
    __syncthreads();
    #pragma unroll
    for (int off = 128; off > 0; off >>= 1) {
        if (tid < off) sdata[tid] += sdata[tid + off];
        __syncthreads();
    }
    if (tid == 0) bsum[blockIdx.x] = sdata[0];
}

__global__ __launch_bounds__(256) void scan2_k(int* __restrict__ bsum)
{
    __shared__ int sdata[256];
    int tid = threadIdx.x;
    int v = (tid < SCAN_B) ? bsum[tid] : 0;
    sdata[tid] = v;
    __syncthreads();
    #pragma unroll
    for (int off = 1; off < 256; off <<= 1) {
        int t = (tid >= off) ? sdata[tid - off] : 0;
        __syncthreads();
        sdata[tid] += t;
        __syncthreads();
    }
    if (tid < SCAN_B) bsum[tid] = sdata[tid] - v;   // exclusive
}

// scan3 + segfill fused (seg[j]=n derivable from block-local scan values)
__global__ __launch_bounds__(256) void scan3_k(const int* __restrict__ cnt,
    const int* __restrict__ bsum, int* __restrict__ rowptr, int* __restrict__ seg)
{
    __shared__ int sdata[256];
    int tid = threadIdx.x;
    int i = blockIdx.x*256 + tid;
    int v = (i < NN) ? cnt[i] : 0;
    sdata[tid] = v;
    __syncthreads();
    #pragma unroll
    for (int off = 1; off < 256; off <<= 1) {
        int t = (tid >= off) ? sdata[tid - off] : 0;
        __syncthreads();
        sdata[tid] += t;
        __syncthreads();
    }
    if (i < NN) {
        int hi = sdata[tid] + bsum[blockIdx.x];
        rowptr[i + 1] = hi;
        for (int j = hi - v; j < hi; ++j) seg[j] = i;
    }
    if (i == 0) rowptr[0] = 0;
}

// scatter colidx (plain store — NT store measured WORSE, round-7 post-mortem)
__global__ __launch_bounds__(256) void scatter_k(const int* __restrict__ rec,
    const int* __restrict__ rowptr, int* __restrict__ cursor, int* __restrict__ colidx)
{
    int e = blockIdx.x*256 + threadIdx.x;
    if (e < NE) {
        int r = rec[e];
        int pos = atomicAdd(&cursor[r], 1);
        colidx[rowptr[r] + pos] = e;
    }
}

// ======================= esum: segsum of raw e_in (16-wide) + fused ssend fill
__global__ __launch_bounds__(256) void esum_k(const float* __restrict__ e_in,
    const int* __restrict__ colidx, const int* __restrict__ seg, const int* __restrict__ send,
    int* __restrict__ ssend, float* __restrict__ esum)
{
    __shared__ int s_ids[256];
    __shared__ int s_seg[256];
    int tid = threadIdx.x;
    int gbase = blockIdx.x*256;
    int id = colidx[gbase + tid];
    s_ids[tid] = id;
    s_seg[tid] = seg[gbase + tid];
    ssend[gbase + tid] = send[id];
    __syncthreads();
    int grp = tid >> 4, c = tid & 15;
    int j0 = grp*16;
    float vv[16];
    #pragma unroll
    for (int jj = 0; jj < 16; ++jj) vv[jj] = e_in[(long)s_ids[j0 + jj]*16 + c];
    float a = 0.f;
    int cur = s_seg[j0];
    #pragma unroll
    for (int jj = 0; jj < 16; ++jj) {
        int n = s_seg[j0 + jj];
        if (n != cur) { atomicAdd(&esum[(long)cur*16 + c], a); a = 0.f; cur = n; }
        a += vv[jj];
    }
    atomicAdd(&esum[(long)cur*16 + c], a);
}

// ======================= device bodies (shared by standalone + mega) ==========

// gsum: 64 edges/wave, LDS ids, 16-deep double-buffered prefetch, lane=column
// contiguous 256B atomic flushes (round-5/7 post-mortems: do NOT change).
template <bool BOTH>
__device__ __forceinline__ void gsum_body(const bf16* __restrict__ hp, int coff,
    const int* __restrict__ ssend, const int* __restrict__ seg,
    float* __restrict__ out1, float* __restrict__ out2,
    int gbase, int* s_ids, int* s_seg)
{
    int tid = threadIdx.x, lane = tid & 63, wv = tid >> 6;
    s_ids[tid] = ssend[gbase + tid];
    s_seg[tid] = seg[gbase + tid];
    __syncthreads();
    int j0 = wv*64;
    const bf16* base = hp + coff + lane;

    unsigned short va[16], vb[16];
    unsigned short wa[BOTH ? 16 : 1], wb[BOTH ? 16 : 1];
    #pragma unroll
    for (int k = 0; k < 16; ++k) {
        long o = (long)s_ids[j0 + k]*128;
        va[k] = *(const unsigned short*)(base + o);
        if (BOTH) wa[k] = *(const unsigned short*)(base + o + 64);
    }
    float a = 0.f, b2 = 0.f;
    int cur = s_seg[j0];
    #pragma unroll
    for (int b = 0; b < 4; ++b) {
        if (b < 3) {
            #pragma unroll
            for (int k = 0; k < 16; ++k) {
                long o = (long)s_ids[j0 + (b+1)*16 + k]*128;
                vb[k] = *(const unsigned short*)(base + o);
                if (BOTH) wb[k] = *(const unsigned short*)(base + o + 64);
            }
        }
        #pragma unroll
        for (int k = 0; k < 16; ++k) {
            int n = s_seg[j0 + b*16 + k];
            if (n != cur) {
                atomicAdd(&out1[(long)cur*64 + lane], a);
                if (BOTH) atomicAdd(&out2[(long)cur*64 + lane], b2);
                a = 0.f; b2 = 0.f; cur = n;
            }
            a += __uint_as_float(((unsigned)va[k]) << 16);
            if (BOTH) b2 += __uint_as_float(((unsigned)wa[k]) << 16);
        }
        if (b < 3) {
            #pragma unroll
            for (int k = 0; k < 16; ++k) { va[k] = vb[k]; if (BOTH) wa[k] = wb[k]; }
        }
    }
    atomicAdd(&out1[(long)cur*64 + lane], a);
    if (BOTH) atomicAdd(&out2[(long)cur*64 + lane], b2);
    __syncthreads();   // LDS reuse across grid-stride tiles
}

// hpemb + eembn fused body (node tile)
__device__ __forceinline__ void hpemb_body(int blk,
    const float* __restrict__ h_in, const float* __restrict__ p_in,
    const float* __restrict__ esum, const int* __restrict__ deg,
    const bf16* __restrict__ wHE, const bf16* __restrict__ wPE, const bf16* __restrict__ wEE,
    const float* __restrict__ he_b, const float* __restrict__ pe_b, const float* __restrict__ ee_b,
    bf16* __restrict__ hp, bf16* __restrict__ eagg)
{
    int tid = threadIdx.x, lane = tid & 63, wv = tid >> 6;
    int l15 = lane & 15, q = lane >> 4;
    int row = blk*64 + wv*16 + l15;
    int rc = (row < NN) ? row : NN - 1;
    f32x4 aH[4], aP[4], aE[4];
    #pragma unroll
    for (int t = 0; t < 4; ++t) {
        float bh = he_b[t*16 + l15], bp = pe_b[t*16 + l15];
        aH[t][0]=bh; aH[t][1]=bh; aH[t][2]=bh; aH[t][3]=bh;
        aP[t][0]=bp; aP[t][1]=bp; aP[t][2]=bp; aP[t][3]=bp;
        aE[t][0]=0;  aE[t][1]=0;  aE[t][2]=0;  aE[t][3]=0;
    }
    #pragma unroll
    for (int c = 0; c < 4; ++c) {
        bf16x8s af = cvt8(h_in + (long)rc*128 + c*32 + q*8);
        #pragma unroll
        for (int t = 0; t < 4; ++t)
            aH[t] = __builtin_amdgcn_mfma_f32_16x16x32_bf16(af, bfrag(wHE, c, t, lane), aH[t], 0, 0, 0);
    }
    {
        bf16x8s af = {0,0,0,0,0,0,0,0};
        if (q < 2) af = cvt8(p_in + (long)rc*16 + q*8);
        #pragma unroll
        for (int t = 0; t < 4; ++t)
            aP[t] = __builtin_amdgcn_mfma_f32_16x16x32_bf16(af, bfrag(wPE, 0, t, lane), aP[t], 0, 0, 0);
    }
    {
        bf16x8s af = {0,0,0,0,0,0,0,0};
        if (q < 2) af = cvt8(esum + (long)rc*16 + q*8);
        #pragma unroll
        for (int t = 0; t < 4; ++t)
            aE[t] = __builtin_amdgcn_mfma_f32_16x16x32_bf16(af, bfrag(wEE, 0, t, lane), aE[t], 0, 0, 0);
    }
    float ebv[4];
    #pragma unroll
    for (int t = 0; t < 4; ++t) ebv[t] = ee_b[t*16 + l15];
    #pragma unroll
    for (int r = 0; r < 4; ++r) {
        int ro = blk*64 + wv*16 + q*4 + r;
        if (ro < NN) {
            float dg = (float)deg[ro];
            #pragma unroll
            for (int t = 0; t < 4; ++t) {
                hp[(long)ro*128 + t*16 + l15]      = __float2bfloat16(aH[t][r]);
                hp[(long)ro*128 + 64 + t*16 + l15] = __float2bfloat16(aP[t][r]);
                eagg[(long)ro*64 + t*16 + l15]     = __float2bfloat16(aE[t][r] + dg*ebv[t]);
            }
        }
    }
}

// hfuse body
__device__ __forceinline__ void hfuse_body(int blk,
    bf16* __restrict__ hp, float* __restrict__ hsum, const float* __restrict__ psum,
    const bf16* __restrict__ eagg, const int* __restrict__ deg,
    const bf16* __restrict__ wAGG, const bf16* __restrict__ wR, const float* __restrict__ mb,
    const bf16* __restrict__ wU, const float* __restrict__ ub, float* __restrict__ out2,
    bf16* sAgg)
{
    int tid = threadIdx.x, lane = tid & 63, wv = tid >> 6;
    int l15 = lane & 15, q = lane >> 4;
    int row = blk*64 + wv*16 + l15;
    int rc = (row < NN) ? row : NN - 1;

    f32x4 aA[4], aR[4];
    #pragma unroll
    for (int t = 0; t < 4; ++t) {
        aA[t][0]=0;aA[t][1]=0;aA[t][2]=0;aA[t][3]=0;
        aR[t][0]=0;aR[t][1]=0;aR[t][2]=0;aR[t][3]=0;
    }
    #pragma unroll
    for (int c = 0; c < 6; ++c) {
        bf16x8s af = (c < 2) ? cvt8(hsum + (long)rc*64 + c*32 + q*8)
                   : (c < 4) ? cvt8(psum + (long)rc*64 + (c-2)*32 + q*8)
                             : *(const bf16x8s*)(eagg + (long)rc*64 + (c-4)*32 + q*8);
        #pragma unroll
        for (int t = 0; t < 4; ++t)
            aA[t] = __builtin_amdgcn_mfma_f32_16x16x32_bf16(af, bfrag(wAGG, c, t, lane), aA[t], 0, 0, 0);
    }
    if (row < NN) {
        float4 z4 = make_float4(0.f, 0.f, 0.f, 0.f);
        #pragma unroll
        for (int c = 0; c < 2; ++c) {
            *(float4*)(hsum + (long)rc*64 + c*32 + q*8)     = z4;
            *(float4*)(hsum + (long)rc*64 + c*32 + q*8 + 4) = z4;
        }
    }
    #pragma unroll
    for (int c = 0; c < 4; ++c) {
        bf16x8s af = *(const bf16x8s*)(hp + (long)rc*128 + c*32 + q*8);
        #pragma unroll
        for (int t = 0; t < 4; ++t)
            aR[t] = __builtin_amdgcn_mfma_f32_16x16x32_bf16(af, bfrag(wR, c, t, lane), aR[t], 0, 0, 0);
    }
    float mbv[4];
    #pragma unroll
    for (int t = 0; t < 4; ++t) mbv[t] = mb[t*16 + l15];
    #pragma unroll
    for (int r = 0; r < 4; ++r) {
        int ro = blk*64 + wv*16 + q*4 + r;
        float dg = (float)deg[(ro < NN) ? ro : NN - 1];
        #pragma unroll
        for (int t = 0; t < 4; ++t)
            sAgg[(wv*16 + q*4 + r)*AGG_STRIDE + t*16 + l15] =
                __float2bfloat16(aA[t][r] + dg*(aR[t][r] + mbv[t]));
    }
    __syncthreads();
    f32x4 acc[4];
    #pragma unroll
    for (int t = 0; t < 4; ++t) { float b = ub[t*16 + l15]; acc[t][0]=b; acc[t][1]=b; acc[t][2]=b; acc[t][3]=b; }
    #pragma unroll
    for (int c = 0; c < 4; ++c) {
        bf16x8s af = (c < 2) ? *(const bf16x8s*)(hp + (long)rc*128 + c*32 + q*8)
                             : *(const bf16x8s*)(sAgg + (wv*16 + l15)*AGG_STRIDE + (c-2)*32 + q*8);
        #pragma unroll
        for (int t = 0; t < 4; ++t)
            acc[t] = __builtin_amdgcn_mfma_f32_16x16x32_bf16(af, bfrag(wU, c, t, lane), acc[t], 0, 0, 0);
    }
    #pragma unroll
    for (int r = 0; r < 4; ++r) {
        int ro = blk*64 + wv*16 + q*4 + r;
        if (ro < NN) {
            #pragma unroll
            for (int t = 0; t < 4; ++t) {
                float fv = acc[t][r];
                hp[(long)ro*128 + t*16 + l15] = __float2bfloat16(fv);
                if (out2) out2[(long)ro*64 + t*16 + l15] = fv;
            }
        }
    }
    __syncthreads();   // sAgg reuse across grid-stride tiles
}

// pfuse body
__device__ __forceinline__ void pfuse_body(int blk,
    bf16* __restrict__ hp, const float* __restrict__ hsumN, float* __restrict__ psum,
    const bf16* __restrict__ eaggIn, bf16* __restrict__ eaggOut, const int* __restrict__ deg,
    const bf16* __restrict__ wEUS, const bf16* __restrict__ wEUR, const bf16* __restrict__ wEUE,
    const float* __restrict__ eub,
    const bf16* __restrict__ wAGG, const bf16* __restrict__ wR, const float* __restrict__ mb,
    const bf16* __restrict__ wU, const float* __restrict__ ub, float* __restrict__ out2,
    bf16* sE, bf16* sAgg)
{
    int tid = threadIdx.x, lane = tid & 63, wv = tid >> 6;
    int l15 = lane & 15, q = lane >> 4;
    int row = blk*64 + wv*16 + l15;
    int rc = (row < NN) ? row : NN - 1;

    f32x4 aE[4], aH[4];
    #pragma unroll
    for (int t = 0; t < 4; ++t) {
        aE[t][0]=0;aE[t][1]=0;aE[t][2]=0;aE[t][3]=0;
        aH[t][0]=0;aH[t][1]=0;aH[t][2]=0;aH[t][3]=0;
    }
    #pragma unroll
    for (int c = 0; c < 4; ++c) {
        bf16x8s af = (c < 2) ? cvt8(hsumN + (long)rc*64 + c*32 + q*8)
                             : *(const bf16x8s*)(eaggIn + (long)rc*64 + (c-2)*32 + q*8);
        #pragma unroll
        for (int t = 0; t < 4; ++t) {
            bf16x8s w = (c < 2) ? bfrag(wEUS, c, t, lane) : bfrag(wEUE, c-2, t, lane);
            aE[t] = __builtin_amdgcn_mfma_f32_16x16x32_bf16(af, w, aE[t], 0, 0, 0);
        }
    }
    #pragma unroll
    for (int c = 0; c < 2; ++c) {
        bf16x8s af = *(const bf16x8s*)(hp + (long)rc*128 + c*32 + q*8);   // h_new
        #pragma unroll
        for (int t = 0; t < 4; ++t)
            aH[t] = __builtin_amdgcn_mfma_f32_16x16x32_bf16(af, bfrag(wEUR, c, t, lane), aH[t], 0, 0, 0);
    }
    float ebv[4];
    #pragma unroll
    for (int t = 0; t < 4; ++t) ebv[t] = eub[t*16 + l15];
    #pragma unroll
    for (int r = 0; r < 4; ++r) {
        int ro = blk*64 + wv*16 + q*4 + r;
        float dg = (float)deg[(ro < NN) ? ro : NN - 1];
        #pragma unroll
        for (int t = 0; t < 4; ++t) {
            bf16 ev = __float2bfloat16(aE[t][r] + dg*(aH[t][r] + ebv[t]));
            sE[(wv*16 + q*4 + r)*AGG_STRIDE + t*16 + l15] = ev;
            if (eaggOut && ro < NN) eaggOut[(long)ro*64 + t*16 + l15] = ev;
        }
    }
    __syncthreads();

    f32x4 aA[4], aR[4];
    #pragma unroll
    for (int t = 0; t < 4; ++t) {
        aA[t][0]=0;aA[t][1]=0;aA[t][2]=0;aA[t][3]=0;
        aR[t][0]=0;aR[t][1]=0;aR[t][2]=0;aR[t][3]=0;
    }
    #pragma unroll
    for (int c = 0; c < 4; ++c) {
        bf16x8s af = (c < 2) ? cvt8(psum + (long)rc*64 + c*32 + q*8)
                             : *(const bf16x8s*)(sE + (wv*16 + l15)*AGG_STRIDE + (c-2)*32 + q*8);
        #pragma unroll
        for (int t = 0; t < 4; ++t)
            aA[t] = __builtin_amdgcn_mfma_f32_16x16x32_bf16(af, bfrag(wAGG, c, t, lane), aA[t], 0, 0, 0);
    }
    if (row < NN) {
        float4 z4 = make_float4(0.f, 0.f, 0.f, 0.f);
        #pragma unroll
        for (int c = 0; c < 2; ++c) {
            *(float4*)(psum + (long)rc*64 + c*32 + q*8)     = z4;
            *(float4*)(psum + (long)rc*64 + c*32 + q*8 + 4) = z4;
        }
    }
    #pragma unroll
    for (int c = 0; c < 2; ++c) {
        bf16x8s af = *(const bf16x8s*)(hp + (long)rc*128 + 64 + c*32 + q*8);
        #pragma unroll
        for (int t = 0; t < 4; ++t)
            aR[t] = __builtin_amdgcn_mfma_f32_16x16x32_bf16(af, bfrag(wR, c, t, lane), aR[t], 0, 0, 0);
    }
    float mbv[4];
    #pragma unroll
    for (int t = 0; t < 4; ++t) mbv[t] = mb[t*16 + l15];
    #pragma unroll
    for (int r = 0; r < 4; ++r) {
        int ro = blk*64 + wv*16 + q*4 + r;
        float dg = (float)deg[(ro < NN) ? ro : NN - 1];
        #pragma unroll
        for (int t = 0; t < 4; ++t)
            sAgg[(wv*16 + q*4 + r)*AGG_STRIDE + t*16 + l15] =
                __float2bfloat16(aA[t][r] + dg*(aR[t][r] + mbv[t]));
    }
    __syncthreads();
    f32x4 acc[4];
    #pragma unroll
    for (int t = 0; t < 4; ++t) { float b = ub[t*16 + l15]; acc[t][0]=b; acc[t][1]=b; acc[t][2]=b; acc[t][3]=b; }
    #pragma unroll
    for (int c = 0; c < 4; ++c) {
        bf16x8s af = (c < 2) ? *(const bf16x8s*)(hp + (long)rc*128 + 64 + c*32 + q*8)
                             : *(const bf16x8s*)(sAgg + (wv*16 + l15)*AGG_STRIDE + (c-2)*32 + q*8);
        #pragma unroll
        for (int t = 0; t < 4; ++t)
            acc[t] = __builtin_amdgcn_mfma_f32_16x16x32_bf16(af, bfrag(wU, c, t, lane), acc[t], 0, 0, 0);
    }
    #pragma unroll
    for (int r = 0; r < 4; ++r) {
        int ro = blk*64 + wv*16 + q*4 + r;
        if (ro < NN) {
            #pragma unroll
            for (int t = 0; t < 4; ++t) {
                float fv = acc[t][r];
                hp[(long)ro*128 + 64 + t*16 + l15] = __float2bfloat16(fv);
                if (out2) out2[(long)ro*64 + t*16 + l15] = fv;
            }
        }
    }
    __syncthreads();   // LDS reuse across grid-stride tiles
}

// ======================= standalone wrappers (fallback path) =================
__global__ __launch_bounds__(256) void hpemb_k(const float* h_in, const float* p_in,
    const float* esum, const int* deg, const bf16* wHE, const bf16* wPE, const bf16* wEE,
    const float* he_b, const float* pe_b, const float* ee_b, bf16* hp, bf16* eagg)
{
    hpemb_body(blockIdx.x, h_in, p_in, esum, deg, wHE, wPE, wEE, he_b, pe_b, ee_b, hp, eagg);
}

template <bool BOTH>
__global__ __launch_bounds__(256) void gsum64_k(const bf16* hp, int coff,
    const int* ssend, const int* seg, float* out1, float* out2)
{
    __shared__ int s_ids[256];
    __shared__ int s_seg[256];
    gsum_body<BOTH>(hp, coff, ssend, seg, out1, out2, blockIdx.x*256, s_ids, s_seg);
}

__global__ __launch_bounds__(256) void hfuse_k(bf16* hp, float* hsum, const float* psum,
    const bf16* eagg, const int* deg, const bf16* wAGG, const bf16* wR, const float* mb,
    const bf16* wU, const float* ub, float* out2)
{
    __shared__ __align__(16) bf16 sAgg[64 * AGG_STRIDE];
    hfuse_body(blockIdx.x, hp, hsum, psum, eagg, deg, wAGG, wR, mb, wU, ub, out2, sAgg);
}

__global__ __launch_bounds__(256) void pfuse_k(bf16* hp, const float* hsumN, float* psum,
    const bf16* eaggIn, bf16* eaggOut, const int* deg,
    const bf16* wEUS, const bf16* wEUR, const bf16* wEUE, const float* eub,
    const bf16* wAGG, const bf16* wR, const float* mb,
    const bf16* wU, const float* ub, float* out2)
{
    __shared__ __align__(16) bf16 sE[64 * AGG_STRIDE];
    __shared__ __align__(16) bf16 sAgg[64 * AGG_STRIDE];
    pfuse_body(blockIdx.x, hp, hsumN, psum, eaggIn, eaggOut, deg, wEUS, wEUR, wEUE, eub,
               wAGG, wR, mb, wU, ub, out2, sE, sAgg);
}

// ======================= cooperative mega kernel =============================
struct MegaArgs {
    const float* h_in; const float* p_in; const float* esum;
    bf16* hp; float* hsum; float* psum; bf16* eaggA; bf16* eaggB;
    const int* ssend; const int* seg; const int* deg;
    const bf16* wf;
    const float* he_b; const float* pe_b; const float* ee_b;
    const float* hm_b; const float* hu_b; const float* eu_b;
    const float* pm_b; const float* pu_b;
    float* dout;
};

__global__ __launch_bounds__(256) void mega_k(MegaArgs a)
{
    __shared__ __align__(16) bf16 smem[2 * 64 * AGG_STRIDE];   // 18432 B
    int* s_ids = (int*)smem;
    int* s_seg = ((int*)smem) + 256;
    bf16* sE   = smem;
    bf16* sAgg = smem + 64 * AGG_STRIDE;
    cg::grid_group grid = cg::this_grid();
    int G = gridDim.x;

    // phase 0: embeddings + eagg0
    for (int t = blockIdx.x; t < NB64; t += G)
        hpemb_body(t, a.h_in, a.p_in, a.esum, a.deg,
                   a.wf + FW_HE, a.wf + FW_PE, a.wf + FW_EE,
                   a.he_b, a.pe_b, a.ee_b, a.hp, a.eaggA);
    grid.sync();
    // phase 0b: bootstrap hsum & psum (one pass, both halves)
    for (int t = blockIdx.x; t < EB; t += G)
        gsum_body<true>(a.hp, 0, a.ssend, a.seg, a.hsum, a.psum, t*256, s_ids, s_seg);
    grid.sync();

    bf16* eA = a.eaggA;
    bf16* eB = a.eaggB;
    for (int i = 0; i < 4; ++i) {
        const bf16* base = a.wf + FW_L0 + (long)i*LSTR;
        for (int t = blockIdx.x; t < NB64; t += G)
            hfuse_body(t, a.hp, a.hsum, a.psum, eA, a.deg,
                       base + R_HAGG, base + R_HMR, a.hm_b + i*64,
                       base + R_HU, a.hu_b + i*64, (i == 3) ? a.dout : nullptr, sAgg);
        grid.sync();
        for (int t = blockIdx.x; t < EB; t += G)
            gsum_body<false>(a.hp, 0, a.ssend, a.seg, a.hsum, nullptr, t*256, s_ids, s_seg);
        grid.sync();
        for (int t = blockIdx.x; t < NB64; t += G)
            pfuse_body(t, a.hp, a.hsum, a.psum, eA, (i < 3) ? eB : nullptr, a.deg,
                       base + R_EUS, base + R_EUR, base + R_EUE, a.eu_b + i*64,
                       base + R_PAGG, base + R_PMR, a.pm_b + i*64,
                       base + R_PU, a.pu_b + i*64,
                       (i == 3) ? a.dout + (long)NN*64 : nullptr, sE, sAgg);
        grid.sync();
        if (i < 3) {
            for (int t = blockIdx.x; t < EB; t += G)
                gsum_body<false>(a.hp, 64, a.ssend, a.seg, a.psum, nullptr, t*256, s_ids, s_seg);
            grid.sync();
        }
        bf16* tmp = eA; eA = eB; eB = tmp;
    }
}

// ======================= launch =======================
extern "C" void kernel_launch(void* const* d_in, const int* in_sizes, int n_in,
                              void* d_out, int out_size, void* d_ws, size_t ws_size,
                              hipStream_t stream)
{
    (void)in_sizes; (void)n_in; (void)out_size; (void)ws_size;
    const float* h_in = (const float*)d_in[0];
    const float* e_in = (const float*)d_in[1];
    const float* p_in = (const float*)d_in[2];
    const int*  ei   = (const int*)d_in[3];
    const int* send = ei;
    const int* rec  = ei + NE;
    const float* he_W = (const float*)d_in[4];  const float* he_b = (const float*)d_in[5];
    const float* ee_W = (const float*)d_in[6];  const float* ee_b = (const float*)d_in[7];
    const float* pe_W = (const float*)d_in[8];  const float* pe_b = (const float*)d_in[9];
    const float* hm_W = (const float*)d_in[10]; const float* hm_b = (const float*)d_in[11];
    const float* hu_W = (const float*)d_in[12]; const float* hu_b = (const float*)d_in[13];
    const float* eu_W = (const float*)d_in[14]; const float* eu_b = (const float*)d_in[15];
    const float* pm_W = (const float*)d_in[16]; const float* pm_b = (const float*)d_in[17];
    const float* pu_W = (const float*)d_in[18]; const float* pu_b = (const float*)d_in[19];

    char* ws = (char*)d_ws;
    bf16* hp     = (bf16*)(ws + OFF_HP);
    float* hsum  = (float*)(ws + OFF_HSUM);
    float* psum  = (float*)(ws + OFF_PSUM);
    float* esum  = (float*)(ws + OFF_ESUM);
    bf16* eaggA  = (bf16*)(ws + OFF_EAGGA);
    bf16* eaggB  = (bf16*)(ws + OFF_EAGGB);
    bf16* wf     = (bf16*)(ws + OFF_WFMT);
    int* rowptr  = (int*)(ws + OFF_ROWPTR);
    int* colidx  = (int*)(ws + OFF_COLIDX);
    int* ssend   = (int*)(ws + OFF_SSEND);
    int* segarr  = (int*)(ws + OFF_SEG);
    int* cnt     = (int*)(ws + OFF_CNT);
    int* bsum    = (int*)(ws + OFF_BSUM);
    float* dout  = (float*)d_out;

    // one-time cooperative-launch capability + grid sizing (host-side queries only)
    static int g_grid = -1;
    if (g_grid < 0) {
        hipDeviceProp_t prop;
        if (hipGetDeviceProperties(&prop, 0) == hipSuccess && prop.cooperativeLaunch) {
            int bpcu = 0;
            if (hipOccupancyMaxActiveBlocksPerMultiprocessor(&bpcu, mega_k, 256, 0) == hipSuccess
                && bpcu >= 1) {
                long g = (long)bpcu * prop.multiProcessorCount;
                g_grid = (int)((g > EB) ? EB : g);
            } else g_grid = 0;
        } else g_grid = 0;
    }

    // CSR build; cnt ends as deg
    (void)hipMemsetAsync(cnt, 0, NN * sizeof(int), stream);
    hist_k<<<EB, 256, 0, stream>>>(rec, cnt);
    scan1_k<<<SCAN_B, 256, 0, stream>>>(cnt, bsum);
    scan2_k<<<1, 256, 0, stream>>>(bsum);
    scan3_k<<<SCAN_B, 256, 0, stream>>>(cnt, bsum, rowptr, segarr);
    (void)hipMemsetAsync(cnt, 0, NN * sizeof(int), stream);
    scatter_k<<<EB, 256, 0, stream>>>(rec, rowptr, cnt, colidx);

    // zero hsum + psum + esum (contiguous; zero-fuse maintains hsum/psum per layer)
    (void)hipMemsetAsync(hsum, 0, (long)NN*(64 + 64 + 16)*sizeof(float), stream);

    esum_k<<<EB, 256, 0, stream>>>(e_in, colidx, segarr, send, ssend, esum);
    wfmt_k<<<39, 256, 0, stream>>>(he_W, ee_W, pe_W, hm_W, hu_W, eu_W, pm_W, pu_W, wf);

    bool coop_done = false;
    if (g_grid > 0) {
        MegaArgs ma;
        ma.h_in = h_in; ma.p_in = p_in; ma.esum = esum;
        ma.hp = hp; ma.hsum = hsum; ma.psum = psum; ma.eaggA = eaggA; ma.eaggB = eaggB;
        ma.ssend = ssend; ma.seg = segarr; ma.deg = cnt; ma.wf = wf;
        ma.he_b = he_b; ma.pe_b = pe_b; ma.ee_b = ee_b;
        ma.hm_b = hm_b; ma.hu_b = hu_b; ma.eu_b = eu_b; ma.pm_b = pm_b; ma.pu_b = pu_b;
        ma.dout = dout;
        void* params[] = { &ma };
        hipError_t err = hipLaunchCooperativeKernel((const void*)mega_k,
            dim3(g_grid), dim3(256), params, 0, stream);
        if (err == hipSuccess) coop_done = true;
        else g_grid = 0;   // never retry
    }

    if (!coop_done) {
        // fallback: proven round-8 dispatch sequence
        hpemb_k<<<NB64, 256, 0, stream>>>(h_in, p_in, esum, cnt,
            wf + FW_HE, wf + FW_PE, wf + FW_EE, he_b, pe_b, ee_b, hp, eaggA);
        gsum64_k<true><<<EB, 256, 0, stream>>>(hp, 0, ssend, segarr, hsum, psum);
        bf16* eA = eaggA;
        bf16* eB = eaggB;
        for (int i = 0; i < 4; ++i) {
            long base = FW_L0 + (long)i*LSTR;
            hfuse_k<<<NB64, 256, 0, stream>>>(hp, hsum, psum, eA, cnt,
                wf + base + R_HAGG, wf + base + R_HMR, hm_b + i*64,
                wf + base + R_HU, hu_b + i*64, (i == 3) ? dout : nullptr);
            gsum64_k<false><<<EB, 256, 0, stream>>>(hp, 0, ssend, segarr, hsum, nullptr);
            pfuse_k<<<NB64, 256, 0, stream>>>(hp, hsum, psum, eA, (i < 3) ? eB : nullptr, cnt,
                wf + base + R_EUS, wf + base + R_EUR, wf + base + R_EUE, eu_b + i*64,
                wf + base + R_PAGG, wf + base + R_PMR, pm_b + i*64,
                wf + base + R_PU, pu_b + i*64,
                (i == 3) ? dout + (long)NN*64 : nullptr);
            if (i < 3)
                gsum64_k<false><<<EB, 256, 0, stream>>>(hp, 64, ssend, segarr, psum, nullptr);
            bf16* tmp = eA; eA = eB; eB = tmp;
        }
    }
}

// Round 11
// 621.016 us; speedup vs baseline: 1.0585x; 1.0021x over previous
//
#include <hip/hip_runtime.h>
#include <hip/hip_bf16.h>

#define NN 50000
#define NE 800000
#define NB64 782                 // ceil(NN/64)
#define EB   3125                // NE/256
#define NODES_PER_XCD 6250       // NN/8

typedef __hip_bfloat16 bf16;
typedef __attribute__((ext_vector_type(8))) short bf16x8s;   // 8 bf16 = 4 VGPRs
typedef __attribute__((ext_vector_type(4))) float f32x4;

// ---- workspace layout (bytes) ----
#define OFF_HP     0L            // hp [NN,128] bf16 : cols 0:64 = h, 64:128 = p
#define OFF_HSUM   12800000L     // hsum [NN,64] f32
#define OFF_PSUM   25600000L     // psum [NN,64] f32
#define OFF_ESUM   38400000L     // esum [NN,16] f32
#define OFF_EAGGA  41600000L     // eaggA [NN,64] bf16
#define OFF_EAGGB  54400000L     // eaggB [NN,64] bf16
#define OFF_WFMT   67200000L     // formatted weights
#define OFF_ROWPTR 67716096L     // (NN+1) int
#define OFF_COLIDX 67916100L     // NE int
#define OFF_SSEND  71116100L     // NE int
#define OFF_SEG    74316100L     // NE int
#define OFF_CNT    77516100L     // NN int (ends as deg)
#define OFF_BSUM   77716100L     // SCAN_B int

#define SCAN_B 196               // ceil(NN/256)

// ---- formatted-weight element offsets (bf16 elems) ----
#define FW_HE 0
#define FW_EE 8192
#define FW_PE 10240
#define FW_L0 12288
#define LSTR  61440
#define R_HAGG 0
#define R_HMR  12288
#define R_HU   20480
#define R_EUS  28672
#define R_EUR  32768
#define R_EUE  36864
#define R_PAGG 40960
#define R_PMR  49152
#define R_PU   53248

#define AGG_STRIDE 72

__device__ __forceinline__ bf16x8s bfrag(const bf16* w, int c, int t, int lane) {
    return *(const bf16x8s*)(w + ((long)(c*4 + t)*64 + lane)*8);
}
__device__ __forceinline__ bf16x8s cvt8(const float* fp) {
    float4 f0 = ((const float4*)fp)[0];
    float4 f1 = ((const float4*)fp)[1];
    bf16 tmp[8];
    tmp[0]=__float2bfloat16(f0.x); tmp[1]=__float2bfloat16(f0.y);
    tmp[2]=__float2bfloat16(f0.z); tmp[3]=__float2bfloat16(f0.w);
    tmp[4]=__float2bfloat16(f1.x); tmp[5]=__float2bfloat16(f1.y);
    tmp[6]=__float2bfloat16(f1.z); tmp[7]=__float2bfloat16(f1.w);
    return *(const bf16x8s*)tmp;
}

// ======================= weight formatting =======================
__global__ __launch_bounds__(256) void wfmt_k(
    const float* __restrict__ he, const float* __restrict__ ee, const float* __restrict__ pe,
    const float* __restrict__ hm, const float* __restrict__ hu, const float* __restrict__ eu,
    const float* __restrict__ pm, const float* __restrict__ pu, bf16* __restrict__ wf)
{
    int s = blockIdx.x;
    const float* src = nullptr; int rowoff = 0, Ksrc = 0, Kpad = 0, mode = 0, split = 0, gap = 0; long doff = 0;
    if      (s == 0) { src = he; Ksrc = 128; Kpad = 128; doff = FW_HE; }
    else if (s == 1) { src = ee; Ksrc = 16;  Kpad = 32;  doff = FW_EE; }
    else if (s == 2) { src = pe; Ksrc = 16;  Kpad = 32;  doff = FW_PE; }
    else {
        int i = (s - 3) / 9, g = (s - 3) % 9;
        long base = FW_L0 + (long)i*LSTR;
        const float* HM = hm + (long)i*320*64;
        const float* HU = hu + (long)i*128*64;
        const float* EU = eu + (long)i*192*64;
        const float* PM = pm + (long)i*192*64;
        const float* PU = pu + (long)i*128*64;
        switch (g) {
          case 0:  src=HM; mode=4; split=128; gap=128; Kpad=192; doff=base+R_HAGG; break;
          case 1:  src=HM; rowoff=128; Ksrc=128; Kpad=128; doff=base+R_HMR;  break;
          case 2:  src=HU; rowoff=0;   Ksrc=128; Kpad=128; doff=base+R_HU;   break;
          case 3:  src=EU; rowoff=0;   Ksrc=64;  Kpad=64;  doff=base+R_EUS;  break;
          case 4:  src=EU; rowoff=64;  Ksrc=64;  Kpad=64;  doff=base+R_EUR;  break;
          case 5:  src=EU; rowoff=128; Ksrc=64;  Kpad=64;  doff=base+R_EUE;  break;
          case 6:  src=PM; mode=4; split=64; gap=64; Kpad=128; doff=base+R_PAGG; break;
          case 7:  src=PM; rowoff=64;  Ksrc=64;  Kpad=64;  doff=base+R_PMR;  break;
          default: src=PU; rowoff=0;   Ksrc=128; Kpad=128; doff=base+R_PU;   break;
        }
    }
    int total = Kpad * 64;
    for (int idx = threadIdx.x; idx < total; idx += 256) {
        int j = idx & 7, l = (idx >> 3) & 63, ct = idx >> 9;
        int c = ct >> 2, t = ct & 3;
        int k = c*32 + (l >> 4)*8 + j;
        int n = t*16 + (l & 15);
        float v;
        if (mode == 4) v = src[(long)(k + (k >= split ? gap : 0))*64 + n];
        else           v = (k < Ksrc) ? src[(long)(rowoff + k)*64 + n] : 0.f;
        wf[doff + idx] = __float2bfloat16(v);
    }
}

// ======================= CSR build =======================
__global__ __launch_bounds__(256) void hist_k(const int* __restrict__ rec, int* __restrict__ cnt)
{
    int e = blockIdx.x*256 + threadIdx.x;
    if (e < NE) atomicAdd(&cnt[rec[e]], 1);
}

__global__ __launch_bounds__(256) void scan1_k(const int* __restrict__ cnt, int* __restrict__ bsum)
{
    __shared__ int sdata[256];
    int tid = threadIdx.x;
    int i = blockIdx.x*256 + tid;
    sdata[tid] = (i < NN) ? cnt[i] : 0;
    __syncthreads();
    #pragma unroll
    for (int off = 128; off > 0; off >>= 1) {
        if (tid < off) sdata[tid] += sdata[tid + off];
        __syncthreads();
    }
    if (tid == 0) bsum[blockIdx.x] = sdata[0];
}

__global__ __launch_bounds__(256) void scan2_k(int* __restrict__ bsum)
{
    __shared__ int sdata[256];
    int tid = threadIdx.x;
    int v = (tid < SCAN_B) ? bsum[tid] : 0;
    sdata[tid] = v;
    __syncthreads();
    #pragma unroll
    for (int off = 1; off < 256; off <<= 1) {
        int t = (tid >= off) ? sdata[tid - off] : 0;
        __syncthreads();
        sdata[tid] += t;
        __syncthreads();
    }
    if (tid < SCAN_B) bsum[tid] = sdata[tid] - v;   // exclusive
}

// scan3 + segfill fused (seg[j]=n derivable from block-local scan values)
__global__ __launch_bounds__(256) void scan3_k(const int* __restrict__ cnt,
    const int* __restrict__ bsum, int* __restrict__ rowptr, int* __restrict__ seg)
{
    __shared__ int sdata[256];
    int tid = threadIdx.x;
    int i = blockIdx.x*256 + tid;
    int v = (i < NN) ? cnt[i] : 0;
    sdata[tid] = v;
    __syncthreads();
    #pragma unroll
    for (int off = 1; off < 256; off <<= 1) {
        int t = (tid >= off) ? sdata[tid - off] : 0;
        __syncthreads();
        sdata[tid] += t;
        __syncthreads();
    }
    if (i < NN) {
        int hi = sdata[tid] + bsum[blockIdx.x];
        rowptr[i + 1] = hi;
        for (int j = hi - v; j < hi; ++j) seg[j] = i;
    }
    if (i == 0) rowptr[0] = 0;
}

// XCD-bucketed scatter: receivers partitioned into 8 contiguous buckets; blocks
// with blockIdx%8==k (round-robin -> XCD k) handle only bucket k, so each XCD's
// colidx writes + cursor atomics stay in a ~400KB L2-local range and MERGE.
// (plain scatter: 55MB write amplification from cross-XCD line bouncing, r4/r8.)
__global__ __launch_bounds__(256) void scatter_k(const int* __restrict__ rec,
    const int* __restrict__ rowptr, int* __restrict__ cursor, int* __restrict__ colidx)
{
    int b = blockIdx.x;
    int bucket = b & 7;
    int e = (b >> 3)*256 + threadIdx.x;
    if (e < NE) {
        int r = rec[e];
        if (r / NODES_PER_XCD == bucket) {
            int pos = atomicAdd(&cursor[r], 1);
            colidx[rowptr[r] + pos] = e;
        }
    }
}

// ======================= esum: segsum of raw e_in (16-wide) + fused ssend fill
__global__ __launch_bounds__(256) void esum_k(const float* __restrict__ e_in,
    const int* __restrict__ colidx, const int* __restrict__ seg, const int* __restrict__ send,
    int* __restrict__ ssend, float* __restrict__ esum)
{
    __shared__ int s_ids[256];
    __shared__ int s_seg[256];
    int tid = threadIdx.x;
    int gbase = blockIdx.x*256;
    int id = colidx[gbase + tid];
    s_ids[tid] = id;
    s_seg[tid] = seg[gbase + tid];
    ssend[gbase + tid] = send[id];
    __syncthreads();
    int grp = tid >> 4, c = tid & 15;
    int j0 = grp*16;
    float vv[16];
    #pragma unroll
    for (int jj = 0; jj < 16; ++jj) vv[jj] = e_in[(long)s_ids[j0 + jj]*16 + c];
    float a = 0.f;
    int cur = s_seg[j0];
    #pragma unroll
    for (int jj = 0; jj < 16; ++jj) {
        int n = s_seg[j0 + jj];
        if (n != cur) { atomicAdd(&esum[(long)cur*16 + c], a); a = 0.f; cur = n; }
        a += vv[jj];
    }
    atomicAdd(&esum[(long)cur*16 + c], a);
}

// ======================= gsum64: segsum of hp[ssend, coff:coff+64] (+BOTH: +64 half)
// lane = column (atomic flushes are one CONTIGUOUS 256B instruction — critical:
// strided flushes cost 6x HBM write amplification, round-5 post-mortem).
// Edge-partitioned (64 edges/wave, 12500 waves — MLP; node-partition at 1/4 the
// waves was 3-5x slower, round-7 post-mortem). ids LDS-staged. 16-deep
// double-buffered register prefetch (depth-32 regressed: VGPR pressure, round-9).
template <bool BOTH>
__global__ __launch_bounds__(256) void gsum64_k(const bf16* __restrict__ hp, int coff,
    const int* __restrict__ ssend, const int* __restrict__ seg,
    float* __restrict__ out1, float* __restrict__ out2)
{
    __shared__ int s_ids[256];
    __shared__ int s_seg[256];
    int tid = threadIdx.x, lane = tid & 63, wv = tid >> 6;
    int gbase = blockIdx.x*256;
    s_ids[tid] = ssend[gbase + tid];
    s_seg[tid] = seg[gbase + tid];
    __syncthreads();
    int j0 = wv*64;
    const bf16* base = hp + coff + lane;

    unsigned short va[16], vb[16];
    unsigned short wa[BOTH ? 16 : 1], wb[BOTH ? 16 : 1];
    #pragma unroll
    for (int k = 0; k < 16; ++k) {
        long o = (long)s_ids[j0 + k]*128;
        va[k] = *(const unsigned short*)(base + o);
        if (BOTH) wa[k] = *(const unsigned short*)(base + o + 64);
    }
    float a = 0.f, b2 = 0.f;
    int cur = s_seg[j0];
    #pragma unroll
    for (int b = 0; b < 4; ++b) {
        if (b < 3) {
            #pragma unroll
            for (int k = 0; k < 16; ++k) {
                long o = (long)s_ids[j0 + (b+1)*16 + k]*128;
                vb[k] = *(const unsigned short*)(base + o);
                if (BOTH) wb[k] = *(const unsigned short*)(base + o + 64);
            }
        }
        #pragma unroll
        for (int k = 0; k < 16; ++k) {
            int n = s_seg[j0 + b*16 + k];
            if (n != cur) {
                atomicAdd(&out1[(long)cur*64 + lane], a);
                if (BOTH) atomicAdd(&out2[(long)cur*64 + lane], b2);
                a = 0.f; b2 = 0.f; cur = n;
            }
            a += __uint_as_float(((unsigned)va[k]) << 16);
            if (BOTH) b2 += __uint_as_float(((unsigned)wa[k]) << 16);
        }
        if (b < 3) {
            #pragma unroll
            for (int k = 0; k < 16; ++k) { va[k] = vb[k]; if (BOTH) wa[k] = wb[k]; }
        }
    }
    atomicAdd(&out1[(long)cur*64 + lane], a);
    if (BOTH) atomicAdd(&out2[(long)cur*64 + lane], b2);
}

// ======================= hpemb + eembn fused =======================
__global__ __launch_bounds__(256) void hpemb_k(const float* __restrict__ h_in,
    const float* __restrict__ p_in, const float* __restrict__ esum, const int* __restrict__ deg,
    const bf16* __restrict__ wHE, const bf16* __restrict__ wPE, const bf16* __restrict__ wEE,
    const float* __restrict__ he_b, const float* __restrict__ pe_b, const float* __restrict__ ee_b,
    bf16* __restrict__ hp, bf16* __restrict__ eagg)
{
    int tid = threadIdx.x, lane = tid & 63, wv = tid >> 6;
    int l15 = lane & 15, q = lane >> 4;
    int row = blockIdx.x*64 + wv*16 + l15;
    int rc = (row < NN) ? row : NN - 1;
    f32x4 aH[4], aP[4], aE[4];
    #pragma unroll
    for (int t = 0; t < 4; ++t) {
        float bh = he_b[t*16 + l15], bp = pe_b[t*16 + l15];
        aH[t][0]=bh; aH[t][1]=bh; aH[t][2]=bh; aH[t][3]=bh;
        aP[t][0]=bp; aP[t][1]=bp; aP[t][2]=bp; aP[t][3]=bp;
        aE[t][0]=0;  aE[t][1]=0;  aE[t][2]=0;  aE[t][3]=0;
    }
    #pragma unroll
    for (int c = 0; c < 4; ++c) {
        bf16x8s af = cvt8(h_in + (long)rc*128 + c*32 + q*8);
        #pragma unroll
        for (int t = 0; t < 4; ++t)
            aH[t] = __builtin_amdgcn_mfma_f32_16x16x32_bf16(af, bfrag(wHE, c, t, lane), aH[t], 0, 0, 0);
    }
    {
        bf16x8s af = {0,0,0,0,0,0,0,0};
        if (q < 2) af = cvt8(p_in + (long)rc*16 + q*8);
        #pragma unroll
        for (int t = 0; t < 4; ++t)
            aP[t] = __builtin_amdgcn_mfma_f32_16x16x32_bf16(af, bfrag(wPE, 0, t, lane), aP[t], 0, 0, 0);
    }
    {
        bf16x8s af = {0,0,0,0,0,0,0,0};
        if (q < 2) af = cvt8(esum + (long)rc*16 + q*8);
        #pragma unroll
        for (int t = 0; t < 4; ++t)
            aE[t] = __builtin_amdgcn_mfma_f32_16x16x32_bf16(af, bfrag(wEE, 0, t, lane), aE[t], 0, 0, 0);
    }
    float ebv[4];
    #pragma unroll
    for (int t = 0; t < 4; ++t) ebv[t] = ee_b[t*16 + l15];
    #pragma unroll
    for (int r = 0; r < 4; ++r) {
        int ro = blockIdx.x*64 + wv*16 + q*4 + r;
        if (ro < NN) {
            float dg = (float)deg[ro];
            #pragma unroll
            for (int t = 0; t < 4; ++t) {
                hp[(long)ro*128 + t*16 + l15]      = __float2bfloat16(aH[t][r]);
                hp[(long)ro*128 + 64 + t*16 + l15] = __float2bfloat16(aP[t][r]);
                eagg[(long)ro*64 + t*16 + l15]     = __float2bfloat16(aE[t][r] + dg*ebv[t]);
            }
        }
    }
}

// hfuse: agg = [hsum|psum|eagg]@HAGG + deg*([h|p]@HMR + hm_b);  h_new = [h|agg]@HU + hu_b
//        zero-fuse: clears hsum (last reader) for the next gsum
__global__ __launch_bounds__(256) void hfuse_k(
    bf16* __restrict__ hp, float* __restrict__ hsum, const float* __restrict__ psum,
    const bf16* __restrict__ eagg, const int* __restrict__ deg,
    const bf16* __restrict__ wAGG, const bf16* __restrict__ wR, const float* __restrict__ mb,
    const bf16* __restrict__ wU, const float* __restrict__ ub, float* __restrict__ out2)
{
    __shared__ __align__(16) bf16 sAgg[64 * AGG_STRIDE];
    int tid = threadIdx.x, lane = tid & 63, wv = tid >> 6;
    int l15 = lane & 15, q = lane >> 4;
    int row = blockIdx.x*64 + wv*16 + l15;
    int rc = (row < NN) ? row : NN - 1;

    f32x4 aA[4], aR[4];
    #pragma unroll
    for (int t = 0; t < 4; ++t) {
        aA[t][0]=0;aA[t][1]=0;aA[t][2]=0;aA[t][3]=0;
        aR[t][0]=0;aR[t][1]=0;aR[t][2]=0;aR[t][3]=0;
    }
    #pragma unroll
    for (int c = 0; c < 6; ++c) {
        bf16x8s af = (c < 2) ? cvt8(hsum + (long)rc*64 + c*32 + q*8)
                   : (c < 4) ? cvt8(psum + (long)rc*64 + (c-2)*32 + q*8)
                             : *(const bf16x8s*)(eagg + (long)rc*64 + (c-4)*32 + q*8);
        #pragma unroll
        for (int t = 0; t < 4; ++t)
            aA[t] = __builtin_amdgcn_mfma_f32_16x16x32_bf16(af, bfrag(wAGG, c, t, lane), aA[t], 0, 0, 0);
    }
    // zero-fuse hsum (owner rows only)
    if (row < NN) {
        float4 z4 = make_float4(0.f, 0.f, 0.f, 0.f);
        #pragma unroll
        for (int c = 0; c < 2; ++c) {
            *(float4*)(hsum + (long)rc*64 + c*32 + q*8)     = z4;
            *(float4*)(hsum + (long)rc*64 + c*32 + q*8 + 4) = z4;
        }
    }
    #pragma unroll
    for (int c = 0; c < 4; ++c) {
        bf16x8s af = *(const bf16x8s*)(hp + (long)rc*128 + c*32 + q*8);
        #pragma unroll
        for (int t = 0; t < 4; ++t)
            aR[t] = __builtin_amdgcn_mfma_f32_16x16x32_bf16(af, bfrag(wR, c, t, lane), aR[t], 0, 0, 0);
    }
    float mbv[4];
    #pragma unroll
    for (int t = 0; t < 4; ++t) mbv[t] = mb[t*16 + l15];
    #pragma unroll
    for (int r = 0; r < 4; ++r) {
        int ro = blockIdx.x*64 + wv*16 + q*4 + r;
        float dg = (float)deg[(ro < NN) ? ro : NN - 1];
        #pragma unroll
        for (int t = 0; t < 4; ++t)
            sAgg[(wv*16 + q*4 + r)*AGG_STRIDE + t*16 + l15] =
                __float2bfloat16(aA[t][r] + dg*(aR[t][r] + mbv[t]));
    }
    __syncthreads();
    f32x4 acc[4];
    #pragma unroll
    for (int t = 0; t < 4; ++t) { float b = ub[t*16 + l15]; acc[t][0]=b; acc[t][1]=b; acc[t][2]=b; acc[t][3]=b; }
    #pragma unroll
    for (int c = 0; c < 4; ++c) {
        bf16x8s af = (c < 2) ? *(const bf16x8s*)(hp + (long)rc*128 + c*32 + q*8)
                             : *(const bf16x8s*)(sAgg + (wv*16 + l15)*AGG_STRIDE + (c-2)*32 + q*8);
        #pragma unroll
        for (int t = 0; t < 4; ++t)
            acc[t] = __builtin_amdgcn_mfma_f32_16x16x32_bf16(af, bfrag(wU, c, t, lane), acc[t], 0, 0, 0);
    }
    #pragma unroll
    for (int r = 0; r < 4; ++r) {
        int ro = blockIdx.x*64 + wv*16 + q*4 + r;
        if (ro < NN) {
            #pragma unroll
            for (int t = 0; t < 4; ++t) {
                float fv = acc[t][r];
                hp[(long)ro*128 + t*16 + l15] = __float2bfloat16(fv);
                if (out2) out2[(long)ro*64 + t*16 + l15] = fv;
            }
        }
    }
}

// pfuse: eaggNew = hsumN@EUS + deg*(h_new@EUR + eu_b) + eaggIn@EUE   (stored bf16)
//        agg = [psum|eaggNew]@PAGG + deg*(p@PMR + pm_b);  p_new = [p|agg]@PU + pu_b
//        zero-fuse: clears psum (last reader)
__global__ __launch_bounds__(256) void pfuse_k(
    bf16* __restrict__ hp, const float* __restrict__ hsumN, float* __restrict__ psum,
    const bf16* __restrict__ eaggIn, bf16* __restrict__ eaggOut, const int* __restrict__ deg,
    const bf16* __restrict__ wEUS, const bf16* __restrict__ wEUR, const bf16* __restrict__ wEUE,
    const float* __restrict__ eub,
    const bf16* __restrict__ wAGG, const bf16* __restrict__ wR, const float* __restrict__ mb,
    const bf16* __restrict__ wU, const float* __restrict__ ub, float* __restrict__ out2)
{
    __shared__ __align__(16) bf16 sE[64 * AGG_STRIDE];
    __shared__ __align__(16) bf16 sAgg[64 * AGG_STRIDE];
    int tid = threadIdx.x, lane = tid & 63, wv = tid >> 6;
    int l15 = lane & 15, q = lane >> 4;
    int row = blockIdx.x*64 + wv*16 + l15;
    int rc = (row < NN) ? row : NN - 1;

    f32x4 aE[4], aH[4];
    #pragma unroll
    for (int t = 0; t < 4; ++t) {
        aE[t][0]=0;aE[t][1]=0;aE[t][2]=0;aE[t][3]=0;
        aH[t][0]=0;aH[t][1]=0;aH[t][2]=0;aH[t][3]=0;
    }
    #pragma unroll
    for (int c = 0; c < 4; ++c) {
        bf16x8s af = (c < 2) ? cvt8(hsumN + (long)rc*64 + c*32 + q*8)
                             : *(const bf16x8s*)(eaggIn + (long)rc*64 + (c-2)*32 + q*8);
        #pragma unroll
        for (int t = 0; t < 4; ++t) {
            bf16x8s w = (c < 2) ? bfrag(wEUS, c, t, lane) : bfrag(wEUE, c-2, t, lane);
            aE[t] = __builtin_amdgcn_mfma_f32_16x16x32_bf16(af, w, aE[t], 0, 0, 0);
        }
    }
    #pragma unroll
    for (int c = 0; c < 2; ++c) {
        bf16x8s af = *(const bf16x8s*)(hp + (long)rc*128 + c*32 + q*8);   // h_new
        #pragma unroll
        for (int t = 0; t < 4; ++t)
            aH[t] = __builtin_amdgcn_mfma_f32_16x16x32_bf16(af, bfrag(wEUR, c, t, lane), aH[t], 0, 0, 0);
    }
    float ebv[4];
    #pragma unroll
    for (int t = 0; t < 4; ++t) ebv[t] = eub[t*16 + l15];
    #pragma unroll
    for (int r = 0; r < 4; ++r) {
        int ro = blockIdx.x*64 + wv*16 + q*4 + r;
        float dg = (float)deg[(ro < NN) ? ro : NN - 1];
        #pragma unroll
        for (int t = 0; t < 4; ++t) {
            bf16 ev = __float2bfloat16(aE[t][r] + dg*(aH[t][r] + ebv[t]));
            sE[(wv*16 + q*4 + r)*AGG_STRIDE + t*16 + l15] = ev;
            if (eaggOut && ro < NN) eaggOut[(long)ro*64 + t*16 + l15] = ev;
        }
    }
    __syncthreads();

    f32x4 aA[4], aR[4];
    #pragma unroll
    for (int t = 0; t < 4; ++t) {
        aA[t][0]=0;aA[t][1]=0;aA[t][2]=0;aA[t][3]=0;
        aR[t][0]=0;aR[t][1]=0;aR[t][2]=0;aR[t][3]=0;
    }
    #pragma unroll
    for (int c = 0; c < 4; ++c) {
        bf16x8s af = (c < 2) ? cvt8(psum + (long)rc*64 + c*32 + q*8)
                             : *(const bf16x8s*)(sE + (wv*16 + l15)*AGG_STRIDE + (c-2)*32 + q*8);
        #pragma unroll
        for (int t = 0; t < 4; ++t)
            aA[t] = __builtin_amdgcn_mfma_f32_16x16x32_bf16(af, bfrag(wAGG, c, t, lane), aA[t], 0, 0, 0);
    }
    // zero-fuse psum (owner rows only)
    if (row < NN) {
        float4 z4 = make_float4(0.f, 0.f, 0.f, 0.f);
        #pragma unroll
        for (int c = 0; c < 2; ++c) {
            *(float4*)(psum + (long)rc*64 + c*32 + q*8)     = z4;
            *(float4*)(psum + (long)rc*64 + c*32 + q*8 + 4) = z4;
        }
    }
    #pragma unroll
    for (int c = 0; c < 2; ++c) {
        bf16x8s af = *(const bf16x8s*)(hp + (long)rc*128 + 64 + c*32 + q*8);
        #pragma unroll
        for (int t = 0; t < 4; ++t)
            aR[t] = __builtin_amdgcn_mfma_f32_16x16x32_bf16(af, bfrag(wR, c, t, lane), aR[t], 0, 0, 0);
    }
    float mbv[4];
    #pragma unroll
    for (int t = 0; t < 4; ++t) mbv[t] = mb[t*16 + l15];
    #pragma unroll
    for (int r = 0; r < 4; ++r) {
        int ro = blockIdx.x*64 + wv*16 + q*4 + r;
        float dg = (float)deg[(ro < NN) ? ro : NN - 1];
        #pragma unroll
        for (int t = 0; t < 4; ++t)
            sAgg[(wv*16 + q*4 + r)*AGG_STRIDE + t*16 + l15] =
                __float2bfloat16(aA[t][r] + dg*(aR[t][r] + mbv[t]));
    }
    __syncthreads();
    f32x4 acc[4];
    #pragma unroll
    for (int t = 0; t < 4; ++t) { float b = ub[t*16 + l15]; acc[t][0]=b; acc[t][1]=b; acc[t][2]=b; acc[t][3]=b; }
    #pragma unroll
    for (int c = 0; c < 4; ++c) {
        bf16x8s af = (c < 2) ? *(const bf16x8s*)(hp + (long)rc*128 + 64 + c*32 + q*8)
                             : *(const bf16x8s*)(sAgg + (wv*16 + l15)*AGG_STRIDE + (c-2)*32 + q*8);
        #pragma unroll
        for (int t = 0; t < 4; ++t)
            acc[t] = __builtin_amdgcn_mfma_f32_16x16x32_bf16(af, bfrag(wU, c, t, lane), acc[t], 0, 0, 0);
    }
    #pragma unroll
    for (int r = 0; r < 4; ++r) {
        int ro = blockIdx.x*64 + wv*16 + q*4 + r;
        if (ro < NN) {
            #pragma unroll
            for (int t = 0; t < 4; ++t) {
                float fv = acc[t][r];
                hp[(long)ro*128 + 64 + t*16 + l15] = __float2bfloat16(fv);
                if (out2) out2[(long)ro*64 + t*16 + l15] = fv;
            }
        }
    }
}

// ======================= launch =======================
extern "C" void kernel_launch(void* const* d_in, const int* in_sizes, int n_in,
                              void* d_out, int out_size, void* d_ws, size_t ws_size,
                              hipStream_t stream)
{
    (void)in_sizes; (void)n_in; (void)out_size; (void)ws_size;
    const float* h_in = (const float*)d_in[0];
    const float* e_in = (const float*)d_in[1];
    const float* p_in = (const float*)d_in[2];
    const int*  ei   = (const int*)d_in[3];
    const int* send = ei;
    const int* rec  = ei + NE;
    const float* he_W = (const float*)d_in[4];  const float* he_b = (const float*)d_in[5];
    const float* ee_W = (const float*)d_in[6];  const float* ee_b = (const float*)d_in[7];
    const float* pe_W = (const float*)d_in[8];  const float* pe_b = (const float*)d_in[9];
    const float* hm_W = (const float*)d_in[10]; const float* hm_b = (const float*)d_in[11];
    const float* hu_W = (const float*)d_in[12]; const float* hu_b = (const float*)d_in[13];
    const float* eu_W = (const float*)d_in[14]; const float* eu_b = (const float*)d_in[15];
    const float* pm_W = (const float*)d_in[16]; const float* pm_b = (const float*)d_in[17];
    const float* pu_W = (const float*)d_in[18]; const float* pu_b = (const float*)d_in[19];

    char* ws = (char*)d_ws;
    bf16* hp     = (bf16*)(ws + OFF_HP);
    float* hsum  = (float*)(ws + OFF_HSUM);
    float* psum  = (float*)(ws + OFF_PSUM);
    float* esum  = (float*)(ws + OFF_ESUM);
    bf16* eaggA  = (bf16*)(ws + OFF_EAGGA);
    bf16* eaggB  = (bf16*)(ws + OFF_EAGGB);
    bf16* wf     = (bf16*)(ws + OFF_WFMT);
    int* rowptr  = (int*)(ws + OFF_ROWPTR);
    int* colidx  = (int*)(ws + OFF_COLIDX);
    int* ssend   = (int*)(ws + OFF_SSEND);
    int* segarr  = (int*)(ws + OFF_SEG);
    int* cnt     = (int*)(ws + OFF_CNT);
    int* bsum    = (int*)(ws + OFF_BSUM);
    float* dout  = (float*)d_out;

    // CSR build; cnt ends as deg
    (void)hipMemsetAsync(cnt, 0, NN * sizeof(int), stream);
    hist_k<<<EB, 256, 0, stream>>>(rec, cnt);
    scan1_k<<<SCAN_B, 256, 0, stream>>>(cnt, bsum);
    scan2_k<<<1, 256, 0, stream>>>(bsum);
    scan3_k<<<SCAN_B, 256, 0, stream>>>(cnt, bsum, rowptr, segarr);
    (void)hipMemsetAsync(cnt, 0, NN * sizeof(int), stream);
    scatter_k<<<EB*8, 256, 0, stream>>>(rec, rowptr, cnt, colidx);

    // zero hsum + psum + esum (contiguous; zero-fuse maintains hsum/psum per layer)
    (void)hipMemsetAsync(hsum, 0, (long)NN*(64 + 64 + 16)*sizeof(float), stream);

    esum_k<<<EB, 256, 0, stream>>>(e_in, colidx, segarr, send, ssend, esum);
    wfmt_k<<<39, 256, 0, stream>>>(he_W, ee_W, pe_W, hm_W, hu_W, eu_W, pm_W, pu_W, wf);

    // embeddings + eagg0 fused; bootstrap hsum & psum in ONE pass
    hpemb_k<<<NB64, 256, 0, stream>>>(h_in, p_in, esum, cnt,
        wf + FW_HE, wf + FW_PE, wf + FW_EE, he_b, pe_b, ee_b, hp, eaggA);
    gsum64_k<true><<<EB, 256, 0, stream>>>(hp, 0, ssend, segarr, hsum, psum);

    bf16* eA = eaggA;
    bf16* eB = eaggB;
    for (int i = 0; i < 4; ++i) {
        long base = FW_L0 + (long)i*LSTR;
        // h update (consumes hsum_i, psum_i, eagg_i; zeroes hsum)
        hfuse_k<<<NB64, 256, 0, stream>>>(hp, hsum, psum, eA, cnt,
            wf + base + R_HAGG, wf + base + R_HMR, hm_b + i*64,
            wf + base + R_HU, hu_b + i*64, (i == 3) ? dout : nullptr);
        // hsum_{i+1} = segsum(h_new[send])
        gsum64_k<false><<<EB, 256, 0, stream>>>(hp, 0, ssend, segarr, hsum, nullptr);
        // p update (computes eagg_{i+1} -> eB; consumes psum_i; zeroes psum)
        pfuse_k<<<NB64, 256, 0, stream>>>(hp, hsum, psum, eA, (i < 3) ? eB : nullptr, cnt,
            wf + base + R_EUS, wf + base + R_EUR, wf + base + R_EUE, eu_b + i*64,
            wf + base + R_PAGG, wf + base + R_PMR, pm_b + i*64,
            wf + base + R_PU, pu_b + i*64,
            (i == 3) ? dout + (long)NN*64 : nullptr);
        // psum_{i+1} = segsum(p_new[send])
        if (i < 3)
            gsum64_k<false><<<EB, 256, 0, stream>>>(hp, 64, ssend, segarr, psum, nullptr);
        bf16* tmp = eA; eA = eB; eB = tmp;
    }
}